// Round 1
// baseline (871.574 us; speedup 1.0000x reference)
//
#include <hip/hip_runtime.h>
#include <math.h>

// ToxicityGATv2 — round 10: agg_csr latency restructure.
//  * per-node esrc preloaded in ONE coalesced load (lane-register), sources
//    extracted via v_readlane -> uniform SGPR base for xlb gathers
//  * 8-edge packs (8 gathers in flight) + masked 4-pack tail (no serial path)
//  * 2-deep node pipeline: next node's (eoff,xr,esrc-chunk) prefetched while
//    computing current node
// Everything else identical to round 9.

constexpr int N_ = 50000;
constexpr int E_ = 400000;
constexpr int G_ = 2000;
constexpr int H_ = 128;
constexpr int IN_ = 39;

typedef __attribute__((ext_vector_type(8))) short bf16x8;
typedef __attribute__((ext_vector_type(4))) float f32x4;

// ---------------- bf16 pack/unpack (RNE) ----------------
__device__ __forceinline__ unsigned pk_bf16(float a, float b) {
  unsigned ua = __float_as_uint(a);
  unsigned ub = __float_as_uint(b);
  ua = (ua + 0x7fffu + ((ua >> 16) & 1u)) >> 16;
  ub = (ub + 0x7fffu + ((ub >> 16) & 1u)) & 0xffff0000u;
  return ua | ub;
}
__device__ __forceinline__ unsigned short bf16_1(float x) {
  unsigned u = __float_as_uint(x);
  u = (u + 0x7fffu + ((u >> 16) & 1u)) >> 16;
  return (unsigned short)u;
}
__device__ __forceinline__ float up_lo(unsigned u) { return __uint_as_float(u << 16); }
__device__ __forceinline__ float up_hi(unsigned u) { return __uint_as_float(u & 0xffff0000u); }

// ---------------- histogram ----------------
__global__ __launch_bounds__(256) void hist_kernel(const int* __restrict__ keys, int n,
                                                   int* __restrict__ cnt) {
  for (int i = blockIdx.x * 256 + threadIdx.x; i < n; i += gridDim.x * 256)
    atomicAdd(&cnt[keys[i]], 1);
}

// ---------------- multi-block scan ----------------
__global__ __launch_bounds__(1024) void scan_local(const int* __restrict__ in,
                                                   int* __restrict__ outx,
                                                   int* __restrict__ bsum, int n) {
  __shared__ int wsum[16];
  int t = threadIdx.x, lane = t & 63, wid = t >> 6;
  int idx = blockIdx.x * 1024 + t;
  int v = (idx < n) ? in[idx] : 0;
  int x = v;
#pragma unroll
  for (int off = 1; off < 64; off <<= 1) {
    int y = __shfl_up(x, off, 64);
    if (lane >= off) x += y;
  }
  if (lane == 63) wsum[wid] = x;
  __syncthreads();
  if (t == 0) {
    int acc = 0;
#pragma unroll
    for (int w = 0; w < 16; w++) { int tmp = wsum[w]; wsum[w] = acc; acc += tmp; }
    bsum[blockIdx.x] = acc;
  }
  __syncthreads();
  if (idx < n) outx[idx] = wsum[wid] + x - v;
}

__global__ __launch_bounds__(64) void scan_bsum(const int* __restrict__ bsum,
                                                int* __restrict__ boff, int nb) {
  int t = threadIdx.x;
  int v = (t < nb) ? bsum[t] : 0;
  int x = v;
#pragma unroll
  for (int off = 1; off < 64; off <<= 1) {
    int y = __shfl_up(x, off, 64);
    if (t >= off) x += y;
  }
  boff[t] = x - v;
}

__global__ __launch_bounds__(1024) void scan_add(int* __restrict__ eoff,
                                                 const int* __restrict__ boff,
                                                 int* __restrict__ cursor, int n) {
  int idx = blockIdx.x * 1024 + threadIdx.x;
  if (idx < n) {
    int e = eoff[idx] + boff[idx >> 10];
    eoff[idx] = e;
    cursor[idx] = e;
  }
  if (idx == 0) eoff[n] = E_;
}

// ---------------- goff from sorted batch ----------------
__global__ __launch_bounds__(256) void goff_from_sorted(const int* __restrict__ batch,
                                                        int* __restrict__ goff) {
  int i = blockIdx.x * 256 + threadIdx.x;
  if (i >= N_) return;
  int bi = batch[i];
  int bp = (i == 0) ? -1 : batch[i - 1];
  for (int g = bp + 1; g <= bi; g++) goff[g] = i;
  if (i == N_ - 1) {
    for (int g = bi + 1; g <= G_; g++) goff[g] = N_;
  }
}

// ---------------- edge scatter (bf16 attrs) ----------------
__global__ __launch_bounds__(256) void edge_scatter(const int* __restrict__ ei,
                                                    const float* __restrict__ ea,
                                                    int* __restrict__ cursor,
                                                    int* __restrict__ esrc,
                                                    unsigned* __restrict__ easb) {
  int e = blockIdx.x * 256 + threadIdx.x;
  if (e >= E_) return;
  int src = ei[e];
  int dst = ei[E_ + e];
  int j = atomicAdd(&cursor[dst], 1);
  esrc[j] = src;
  const float4* eav = (const float4*)(ea + (size_t)e * 8);
  float4 a0 = eav[0], a1 = eav[1];
  uint4 o;
  o.x = pk_bf16(a0.x, a0.y);
  o.y = pk_bf16(a0.z, a0.w);
  o.z = pk_bf16(a1.x, a1.y);
  o.w = pk_bf16(a1.z, a1.w);
  ((uint4*)easb)[j] = o;
}

// ---------------- weight pre-pack: wpack[l][n][k] = bf16([Wl|Wr][k][n]) -------
__global__ __launch_bounds__(256) void pack_weights(const float* __restrict__ Wl,
                                                    const float* __restrict__ Wr,
                                                    unsigned short* __restrict__ wpack) {
  int i = blockIdx.x * 256 + threadIdx.x;  // enumerate (l, k, n) read-coalesced
  if (i >= 3 * 128 * 256) return;
  int l = i >> 15;
  int rem = i & 32767;
  int k = rem >> 8;
  int n = rem & 255;
  const float* Wsrc = (n < 128) ? (Wl + l * H_ * H_) : (Wr + l * H_ * H_);
  int nn = n & 127;
  wpack[(size_t)l * 32768 + n * 128 + k] = bf16_1(Wsrc[k * H_ + nn]);
}

// ---------------- input GEMM + fused colstats ----------------
__global__ __launch_bounds__(256) void in_gemm(const float* __restrict__ x,
                                               const float* __restrict__ W,
                                               const float* __restrict__ b,
                                               float* __restrict__ y,
                                               float* __restrict__ ssum,
                                               float* __restrict__ ssq) {
  __shared__ float xs[32][40];
  __shared__ float s1[256], s2[256];
  int t = threadIdx.x;
  int row0 = blockIdx.x * 32;
  for (int i = t; i < 32 * IN_; i += 256) {
    int r = i / IN_, k = i % IN_;
    int row = row0 + r;
    xs[r][k] = (row < N_) ? x[row * IN_ + k] : 0.f;
  }
  __syncthreads();
  int col = t & 127;
  int half = t >> 7;
  float acc[16];
#pragma unroll
  for (int r = 0; r < 16; r++) acc[r] = 0.f;
  for (int k = 0; k < IN_; k++) {
    float w = W[k * H_ + col];
#pragma unroll
    for (int r = 0; r < 16; r++) acc[r] = fmaf(xs[half * 16 + r][k], w, acc[r]);
  }
  float bb = b[col];
  float a1 = 0.f, a2 = 0.f;
#pragma unroll
  for (int r = 0; r < 16; r++) {
    int row = row0 + half * 16 + r;
    float v = acc[r] + bb;
    if (row < N_) {
      y[row * H_ + col] = v;
      a1 += v;
      a2 = fmaf(v, v, a2);
    }
  }
  s1[t] = a1; s2[t] = a2;
  __syncthreads();
  if (t < 128) {
    atomicAdd(&ssum[t], s1[t] + s1[t + 128]);
    atomicAdd(&ssq[t], s2[t] + s2[t + 128]);
  }
}

// ---------------- MFMA node GEMM (pre-packed bf16 B) ----------
// MODE 1: v=relu(bn(buf)); xn=v.  MODE 2: v=xn+elu(bn(buf)); xn=v.
template <int MODE>
__global__ __launch_bounds__(256) void gemm_mfma(float* __restrict__ xn,
                                                 const float* __restrict__ buf,
                                                 const float* __restrict__ g,
                                                 const float* __restrict__ beta,
                                                 const float* __restrict__ ssum,
                                                 const float* __restrict__ ssq,
                                                 float rows_inv,
                                                 const unsigned short* __restrict__ wp,
                                                 unsigned* __restrict__ xlb,
                                                 unsigned* __restrict__ xrb) {
  __shared__ char smem[17408 + 20480];
  short (*a_s)[136] = (short(*)[136])smem;              // 64 rows x 128 k (pad 136)
  short (*b_s)[40] = (short(*)[40])(smem + 17408);      // 256 n x 32 k (pad 40)
  float* t2base = (float*)(smem + 17408);               // epilogue reuse
  int t = threadIdx.x;
  int lane = t & 63, w = t >> 6;
  int quad = lane >> 4, lc = lane & 15;
  int row0 = blockIdx.x * 64;

  // ---- stage A (fused BN epilogue, fp32 xn updated, bf16 into LDS) ----
  {
    int r = t >> 2;
    int row = row0 + r;
    int kb0 = (t & 3) * 32;
    bool valid = row < N_;
    for (int kk = 0; kk < 32; kk += 4) {
      int c = kb0 + kk;
      float4 v = make_float4(0.f, 0.f, 0.f, 0.f);
      if (valid) {
        float4 bv = *(const float4*)&buf[(size_t)row * H_ + c];
        float4 gv = *(const float4*)&g[c];
        float4 be = *(const float4*)&beta[c];
        float4 s1 = *(const float4*)&ssum[c];
        float4 s2 = *(const float4*)&ssq[c];
        float m0 = s1.x * rows_inv, m1 = s1.y * rows_inv, m2 = s1.z * rows_inv, m3 = s1.w * rows_inv;
        float r0 = rsqrtf(s2.x * rows_inv - m0 * m0 + 1e-5f);
        float r1 = rsqrtf(s2.y * rows_inv - m1 * m1 + 1e-5f);
        float r2 = rsqrtf(s2.z * rows_inv - m2 * m2 + 1e-5f);
        float r3 = rsqrtf(s2.w * rows_inv - m3 * m3 + 1e-5f);
        float t0 = gv.x * (bv.x - m0) * r0 + be.x;
        float t1 = gv.y * (bv.y - m1) * r1 + be.y;
        float t2 = gv.z * (bv.z - m2) * r2 + be.z;
        float t3 = gv.w * (bv.w - m3) * r3 + be.w;
        if (MODE == 1) {
          v = make_float4(fmaxf(t0, 0.f), fmaxf(t1, 0.f), fmaxf(t2, 0.f), fmaxf(t3, 0.f));
        } else {
          float4 xo = *(const float4*)&xn[(size_t)row * H_ + c];
          v.x = xo.x + ((t0 > 0.f) ? t0 : (__expf(t0) - 1.f));
          v.y = xo.y + ((t1 > 0.f) ? t1 : (__expf(t1) - 1.f));
          v.z = xo.z + ((t2 > 0.f) ? t2 : (__expf(t2) - 1.f));
          v.w = xo.w + ((t3 > 0.f) ? t3 : (__expf(t3) - 1.f));
        }
        *(float4*)&xn[(size_t)row * H_ + c] = v;
      }
      uint2 pk;
      pk.x = pk_bf16(v.x, v.y);
      pk.y = pk_bf16(v.z, v.w);
      *(uint2*)&a_s[r][c] = pk;
    }
  }

  f32x4 acc[16];
#pragma unroll
  for (int nt = 0; nt < 16; nt++) acc[nt] = (f32x4){0.f, 0.f, 0.f, 0.f};

  for (int kb = 0; kb < 4; kb++) {
    __syncthreads();
    // stage B chunk: vectorized copy from pre-packed weights (16 KB)
    for (int i = t; i < 1024; i += 256) {
      int n = i >> 2;
      int k8 = (i & 3) * 8;
      *(uint4*)&b_s[n][k8] = *(const uint4*)&wp[(size_t)n * 128 + kb * 32 + k8];
    }
    __syncthreads();
    bf16x8 av = *(const bf16x8*)&a_s[w * 16 + lc][kb * 32 + quad * 8];
#pragma unroll
    for (int nt = 0; nt < 16; nt++) {
      bf16x8 bv = *(const bf16x8*)&b_s[nt * 16 + lc][quad * 8];
      acc[nt] = __builtin_amdgcn_mfma_f32_16x16x32_bf16(av, bv, acc[nt], 0, 0, 0);
    }
  }
  __syncthreads();  // b_s -> t2 reuse

  // ---- epilogue: transpose 16x32 chunks via LDS, packed coalesced stores ----
  float* t2 = t2base + w * 544;  // 16 rows x 34 cols fp32, per-wave private
  for (int ntp = 0; ntp < 8; ntp++) {
#pragma unroll
    for (int rr = 0; rr < 4; rr++) {
      t2[(quad * 4 + rr) * 34 + lc] = acc[2 * ntp][rr];
      t2[(quad * 4 + rr) * 34 + 16 + lc] = acc[2 * ntp + 1][rr];
    }
    __asm__ volatile("s_waitcnt lgkmcnt(0)" ::: "memory");
#pragma unroll
    for (int it = 0; it < 4; it++) {
      int item = lane + it * 64;
      int p = item & 15, rowi = item >> 4;
      float v0 = t2[rowi * 34 + 2 * p];
      float v1 = t2[rowi * 34 + 2 * p + 1];
      unsigned u = pk_bf16(v0, v1);
      int colpair = ntp * 16 + p;
      int rowg = row0 + w * 16 + rowi;
      if (rowg < N_) {
        if (colpair < 64) xlb[(size_t)rowg * 64 + colpair] = u;
        else xrb[(size_t)rowg * 64 + colpair - 64] = u;
      }
    }
    __asm__ volatile("s_waitcnt lgkmcnt(0)" ::: "memory");
  }
}

// ---------------- CSR aggregation (round-10 pipelined body) ----------------
__device__ __forceinline__ float ep8u(const uint4& u, const float (&w)[8]) {
  float ep = up_lo(u.x) * w[0];
  ep = fmaf(up_hi(u.x), w[1], ep);
  ep = fmaf(up_lo(u.y), w[2], ep);
  ep = fmaf(up_hi(u.y), w[3], ep);
  ep = fmaf(up_lo(u.z), w[4], ep);
  ep = fmaf(up_hi(u.z), w[5], ep);
  ep = fmaf(up_lo(u.w), w[6], ep);
  ep = fmaf(up_hi(u.w), w[7], ep);
  return ep;
}

// Process W edges starting at j (within chunk at `base`, cnt valid edges).
// Sources come from the preloaded lane register `spre` via v_readlane ->
// uniform SGPR, so gathers issue immediately with no esrc-load dependency.
// MASK=true clamps indices (duplicate loads) and zeroes padded exps.
template <int W, bool MASK>
__device__ __forceinline__ void edge_pack(int spre, int j, int cnt, int base, int l,
                                          const unsigned* __restrict__ xlb,
                                          const uint4* __restrict__ eas4,
                                          float xr0, float xr1,
                                          const float (&w0)[8], const float (&w1)[8],
                                          float2 attv,
                                          float& acc0, float& acc1, float& den) {
  int ss[W];
  unsigned xu[W];
  uint4 u[W];
#pragma unroll
  for (int q = 0; q < W; q++) {
    int idx = j + q;
    int cl = MASK ? ((idx < cnt) ? idx : (cnt - 1)) : idx;
    ss[q] = __builtin_amdgcn_readlane(spre, cl);
  }
#pragma unroll
  for (int q = 0; q < W; q++) xu[q] = xlb[(size_t)ss[q] * 64 + l];
#pragma unroll
  for (int q = 0; q < W; q++) {
    int idx = j + q;
    int cl = MASK ? ((idx < cnt) ? idx : (cnt - 1)) : idx;
    u[q] = eas4[base + cl];
  }
  float p[W], x0[W], x1[W];
#pragma unroll
  for (int q = 0; q < W; q++) {
    x0[q] = up_lo(xu[q]);
    x1[q] = up_hi(xu[q]);
    float m0 = x0[q] + xr0 + ep8u(u[q], w0);
    float m1 = x1[q] + xr1 + ep8u(u[q], w1);
    m0 = (m0 > 0.f) ? m0 : 0.2f * m0;
    m1 = (m1 > 0.f) ? m1 : 0.2f * m1;
    p[q] = fmaf(m0, attv.x, m1 * attv.y);
  }
#pragma unroll
  for (int off = 8; off > 0; off >>= 1)
#pragma unroll
    for (int q = 0; q < W; q++) p[q] += __shfl_xor(p[q], off, 64);
#pragma unroll
  for (int q = 0; q < W; q++) {
    float ev = __expf(p[q]);
    if (MASK && (j + q >= cnt)) ev = 0.f;
    acc0 = fmaf(ev, x0[q], acc0);
    acc1 = fmaf(ev, x1[q], acc1);
    den += ev;
  }
}

__global__ __launch_bounds__(256) void agg_csr(const int* __restrict__ eoff,
                                               const int* __restrict__ esrc,
                                               const unsigned* __restrict__ easb,
                                               const float* __restrict__ Wel,
                                               const float* __restrict__ attl,
                                               const unsigned* __restrict__ xlb,
                                               const unsigned* __restrict__ xrb,
                                               const float* __restrict__ cb,
                                               float* __restrict__ buf,
                                               float* __restrict__ ssum,
                                               float* __restrict__ ssq) {
  __shared__ float sA[256], sB[256], sC[256], sD[256];
  int t = threadIdx.x;
  int l = t & 63;
  int sub = t >> 6;
  int c0 = l * 2;
  float w0[8], w1[8];
#pragma unroll
  for (int k = 0; k < 8; k++) {
    float2 wv = *(const float2*)&Wel[k * H_ + c0];
    w0[k] = wv.x; w1[k] = wv.y;
  }
  float2 attv = *(const float2*)&attl[c0];
  float2 cbv = *(const float2*)&cb[c0];
  const uint4* eas4 = (const uint4*)easb;
  float a1_0 = 0.f, a1_1 = 0.f, a2_0 = 0.f, a2_1 = 0.f;

  const int stride = gridDim.x * 4;
  int n0 = blockIdx.x * 4 + sub;

  // ---- 2-deep node pipeline state ----
  int cur_e0 = 0, cur_e1 = 0, cur_spre = 0;
  unsigned cur_xr = 0;
  int nx_e0 = 0, nx_e1 = 0;
  unsigned nx_xr = 0;
  if (n0 < N_) {
    cur_e0 = eoff[n0];
    cur_e1 = eoff[n0 + 1];
    cur_xr = xrb[(size_t)n0 * 64 + l];
    cur_spre = (cur_e0 + l < cur_e1) ? esrc[cur_e0 + l] : 0;
    int n1 = n0 + stride;
    if (n1 < N_) {
      nx_e0 = eoff[n1];
      nx_e1 = eoff[n1 + 1];
      nx_xr = xrb[(size_t)n1 * 64 + l];
    }
  }

  for (int n = n0; n < N_; n += stride) {
    int e0 = cur_e0, e1 = cur_e1, spre = cur_spre;
    unsigned xru = cur_xr;
    int n1 = n + stride;
    int n2 = n + 2 * stride;

    // issue next node's esrc preload (address already resident) and
    // next-next node's (eoff, xr) — all overlap with this node's compute
    int nspre = 0;
    if (n1 < N_) nspre = (nx_e0 + l < nx_e1) ? esrc[nx_e0 + l] : 0;
    int n2_e0 = 0, n2_e1 = 0;
    unsigned n2_xr = 0;
    if (n2 < N_) {
      n2_e0 = eoff[n2];
      n2_e1 = eoff[n2 + 1];
      n2_xr = xrb[(size_t)n2 * 64 + l];
    }

    float xr0 = up_lo(xru), xr1 = up_hi(xru);
    float acc0 = 0.f, acc1 = 0.f, den = 0.f;

    for (int base = e0; base < e1; base += 64) {
      int cnt = min(64, e1 - base);
      if (base != e0) spre = (base + l < e1) ? esrc[base + l] : 0;
      int j = 0;
      for (; j + 8 <= cnt; j += 8)
        edge_pack<8, false>(spre, j, cnt, base, l, xlb, eas4, xr0, xr1, w0, w1, attv,
                            acc0, acc1, den);
      for (; j < cnt; j += 4)
        edge_pack<4, true>(spre, j, cnt, base, l, xlb, eas4, xr0, xr1, w0, w1, attv,
                           acc0, acc1, den);
    }

    float inv = 1.f / (den + 1e-16f);
    float h0 = acc0 * inv + cbv.x;
    float h1 = acc1 * inv + cbv.y;
    *(float2*)&buf[(size_t)n * H_ + c0] = make_float2(h0, h1);
    a1_0 += h0; a1_1 += h1;
    a2_0 = fmaf(h0, h0, a2_0); a2_1 = fmaf(h1, h1, a2_1);

    // rotate pipeline
    cur_e0 = nx_e0; cur_e1 = nx_e1; cur_xr = nx_xr; cur_spre = nspre;
    nx_e0 = n2_e0; nx_e1 = n2_e1; nx_xr = n2_xr;
  }

  sA[t] = a1_0; sB[t] = a1_1; sC[t] = a2_0; sD[t] = a2_1;
  __syncthreads();
  if (t < 64) {
    float r1 = sA[t] + sA[t + 64] + sA[t + 128] + sA[t + 192];
    float r2 = sB[t] + sB[t + 64] + sB[t + 128] + sB[t + 192];
    float r3 = sC[t] + sC[t + 64] + sC[t + 128] + sC[t + 192];
    float r4 = sD[t] + sD[t + 64] + sD[t + 128] + sD[t + 192];
    atomicAdd(&ssum[2 * t], r1);
    atomicAdd(&ssum[2 * t + 1], r2);
    atomicAdd(&ssq[2 * t], r3);
    atomicAdd(&ssq[2 * t + 1], r4);
  }
}

// ---------------- BN apply with inline finalize ----------------
__global__ __launch_bounds__(256) void apply_bn_relu(const float* __restrict__ y,
                                                     float* __restrict__ out,
                                                     const float* __restrict__ g,
                                                     const float* __restrict__ beta,
                                                     const float* __restrict__ ssum,
                                                     const float* __restrict__ ssq,
                                                     float rows_inv,
                                                     long total, int cmask) {
  long i = (long)blockIdx.x * 256 + threadIdx.x;
  if (i >= total) return;
  int c = (int)i & cmask;
  float m = ssum[c] * rows_inv;
  float rs = rsqrtf(ssq[c] * rows_inv - m * m + 1e-5f);
  float v = g[c] * (y[i] - m) * rs + beta[c];
  out[i] = fmaxf(v, 0.f);
}

// ---------------- pooling with fused layer-2 residual (inline BN finalize) ----
__global__ __launch_bounds__(128) void pool_residual(const int* __restrict__ goff,
                                                     const float* __restrict__ xn,
                                                     const float* __restrict__ buf,
                                                     const float* __restrict__ g,
                                                     const float* __restrict__ beta,
                                                     const float* __restrict__ ssum,
                                                     const float* __restrict__ ssq,
                                                     float rows_inv,
                                                     float* __restrict__ xg) {
  int gr = blockIdx.x;
  int t = threadIdx.x;
  int n0 = goff[gr], n1 = goff[gr + 1];
  float mm = ssum[t] * rows_inv;
  float rr = rsqrtf(ssq[t] * rows_inv - mm * mm + 1e-5f);
  float gg = g[t], bb = beta[t];
  float s = 0.f, mx = -INFINITY;
  for (int n = n0; n < n1; n++) {
    float w = gg * (buf[(size_t)n * H_ + t] - mm) * rr + bb;
    w = (w > 0.f) ? w : (__expf(w) - 1.f);
    float v = xn[(size_t)n * H_ + t] + w;
    s += v;
    mx = fmaxf(mx, v);
  }
  float c = (float)(n1 - n0);
  xg[gr * 384 + t] = s / fmaxf(c, 1.f);
  xg[gr * 384 + 128 + t] = (c > 0.f) ? mx : 0.f;
  xg[gr * 384 + 256 + t] = s;
}

// ---------------- MLP GEMMs (fused colstats) ----------------
template <int K, int COLS>
__global__ void mlp_gemm(const float* __restrict__ A, const float* __restrict__ W,
                         const float* __restrict__ b, float* __restrict__ Y, int rows,
                         float* __restrict__ ssum, float* __restrict__ ssq) {
  __shared__ float xs[8][K];
  int t = threadIdx.x;
  int row0 = blockIdx.x * 8;
  for (int i = t; i < 8 * K; i += COLS) {
    int r = i / K, k = i % K;
    int row = row0 + r;
    xs[r][k] = (row < rows) ? A[row * K + k] : 0.f;
  }
  __syncthreads();
  float acc[8];
#pragma unroll
  for (int r = 0; r < 8; r++) acc[r] = 0.f;
  for (int k = 0; k < K; k++) {
    float w = W[k * COLS + t];
#pragma unroll
    for (int r = 0; r < 8; r++) acc[r] = fmaf(xs[r][k], w, acc[r]);
  }
  float bb = b[t];
  float a1 = 0.f, a2 = 0.f;
#pragma unroll
  for (int r = 0; r < 8; r++) {
    int row = row0 + r;
    if (row < rows) {
      float v = acc[r] + bb;
      Y[row * COLS + t] = v;
      a1 += v;
      a2 = fmaf(v, v, a2);
    }
  }
  atomicAdd(&ssum[t], a1);
  atomicAdd(&ssq[t], a2);
}

// ---------------- head ----------------
__global__ __launch_bounds__(64) void head_kernel(const float* __restrict__ u,
                                                  const float* __restrict__ W,
                                                  const float* __restrict__ b,
                                                  float* __restrict__ out) {
  __shared__ float row[128];
  int g = blockIdx.x;
  int t = threadIdx.x;
  row[t] = u[g * 128 + t];
  row[t + 64] = u[g * 128 + 64 + t];
  __syncthreads();
  if (t < 12) {
    float acc = b[t];
    for (int k = 0; k < 128; k++) acc = fmaf(row[k], W[k * 12 + t], acc);
    out[g * 12 + t] = 1.f / (1.f + expf(-acc));
  }
}

// ---------------- launcher ----------------
extern "C" void kernel_launch(void* const* d_in, const int* in_sizes, int n_in, void* d_out,
                              int out_size, void* d_ws, size_t ws_size, hipStream_t stream) {
  (void)in_sizes; (void)n_in; (void)out_size; (void)ws_size;
  const float* x       = (const float*)d_in[0];
  const int*   ei      = (const int*)d_in[1];
  const float* ea      = (const float*)d_in[2];
  const int*   batch   = (const int*)d_in[3];
  const float* in_W    = (const float*)d_in[4];
  const float* in_b    = (const float*)d_in[5];
  const float* in_g    = (const float*)d_in[6];
  const float* in_beta = (const float*)d_in[7];
  const float* Wl      = (const float*)d_in[8];
  const float* Wr      = (const float*)d_in[9];
  const float* We      = (const float*)d_in[10];
  const float* att     = (const float*)d_in[11];
  const float* conv_b  = (const float*)d_in[12];
  const float* bn_g    = (const float*)d_in[13];
  const float* bn_b    = (const float*)d_in[14];
  const float* t1_W    = (const float*)d_in[15];
  const float* t1_b    = (const float*)d_in[16];
  const float* t1_g    = (const float*)d_in[17];
  const float* t1_beta = (const float*)d_in[18];
  const float* t2_W    = (const float*)d_in[19];
  const float* t2_b    = (const float*)d_in[20];
  const float* t2_g    = (const float*)d_in[21];
  const float* t2_beta = (const float*)d_in[22];
  const float* head_W  = (const float*)d_in[23];
  const float* head_b  = (const float*)d_in[24];
  float* out = (float*)d_out;

  float* p = (float*)d_ws;
  float* xn    = p; p += N_ * H_;
  float* buf   = p; p += N_ * H_;
  float* sstat = p; p += 6 * 512;   // 6 stages x (ssum 256 | ssq 256)
  float* xg    = p; p += G_ * 384;
  float* u1    = p; p += G_ * 256;
  float* u2    = p; p += G_ * 128;
  unsigned* up = (unsigned*)p;
  unsigned* xlb  = up; up += (size_t)N_ * 64;
  unsigned* xrb  = up; up += (size_t)N_ * 64;
  unsigned* easb = up; up += (size_t)E_ * 4;
  unsigned short* wpack = (unsigned short*)up; up += 3 * 32768 / 2;
  int* ip = (int*)up;
  int* deg    = ip; ip += N_;
  int* eoff   = ip; ip += N_ + 1;
  int* cursor = ip; ip += N_;
  int* goff   = ip; ip += G_ + 1;
  int* esrc   = ip; ip += E_;
  int* bsum   = ip; ip += 64;
  int* boff   = ip; ip += 64;

#define SSUM(s) (sstat + (s) * 512)
#define SSQ(s)  (sstat + (s) * 512 + 256)

  // ---- build CSR structures + pre-pack weights ----
  hipMemsetAsync(deg, 0, (size_t)N_ * sizeof(int), stream);
  hipMemsetAsync(sstat, 0, 6 * 512 * sizeof(float), stream);
  hist_kernel<<<1024, 256, 0, stream>>>(ei + E_, E_, deg);
  scan_local<<<49, 1024, 0, stream>>>(deg, eoff, bsum, N_);
  scan_bsum<<<1, 64, 0, stream>>>(bsum, boff, 49);
  scan_add<<<49, 1024, 0, stream>>>(eoff, boff, cursor, N_);
  edge_scatter<<<(E_ + 255) / 256, 256, 0, stream>>>(ei, ea, cursor, esrc, easb);
  goff_from_sorted<<<(N_ + 255) / 256, 256, 0, stream>>>(batch, goff);
  pack_weights<<<384, 256, 0, stream>>>(Wl, Wr, wpack);

  // ---- input layer (stats -> stage 0) ----
  in_gemm<<<(N_ + 31) / 32, 256, 0, stream>>>(x, in_W, in_b, buf, SSUM(0), SSQ(0));

  // ---- 3 GATv2 layers (conv stats of layer l -> stage l+1) ----
  const float rnInv = 1.f / N_;
  for (int l = 0; l < 3; l++) {
    if (l == 0) {
      gemm_mfma<1><<<782, 256, 0, stream>>>(xn, buf, in_g, in_beta, SSUM(0), SSQ(0), rnInv,
                                            wpack + (size_t)l * 32768, xlb, xrb);
    } else {
      gemm_mfma<2><<<782, 256, 0, stream>>>(xn, buf, bn_g + (l - 1) * H_, bn_b + (l - 1) * H_,
                                            SSUM(l), SSQ(l), rnInv,
                                            wpack + (size_t)l * 32768, xlb, xrb);
    }
    agg_csr<<<2048, 256, 0, stream>>>(eoff, esrc, easb, We + l * 8 * H_, att + l * H_,
                                      xlb, xrb, conv_b + l * H_, buf, SSUM(l + 1), SSQ(l + 1));
  }

  // ---- pooling with fused layer-2 residual (stage 3 stats) ----
  pool_residual<<<G_, 128, 0, stream>>>(goff, xn, buf, bn_g + 2 * H_, bn_b + 2 * H_,
                                        SSUM(3), SSQ(3), rnInv, xg);

  // ---- t1 (stats -> stage 4) ----
  const float rgInv = 1.f / G_;
  mlp_gemm<384, 256><<<G_ / 8, 256, 0, stream>>>(xg, t1_W, t1_b, u1, G_, SSUM(4), SSQ(4));
  apply_bn_relu<<<(G_ * 256 + 255) / 256, 256, 0, stream>>>(u1, u1, t1_g, t1_beta,
                                                            SSUM(4), SSQ(4), rgInv,
                                                            (long)G_ * 256, 255);

  // ---- t2 (stats -> stage 5) ----
  mlp_gemm<256, 128><<<G_ / 8, 128, 0, stream>>>(u1, t2_W, t2_b, u2, G_, SSUM(5), SSQ(5));
  apply_bn_relu<<<(G_ * 128 + 255) / 256, 256, 0, stream>>>(u2, u2, t2_g, t2_beta,
                                                            SSUM(5), SSQ(5), rgInv,
                                                            (long)G_ * 128, 127);

  // ---- head ----
  head_kernel<<<G_, 64, 0, stream>>>(u2, head_W, head_b, out);
#undef SSUM
#undef SSQ
}

// Round 2
// 853.622 us; speedup vs baseline: 1.0210x; 1.0210x over previous
//
#include <hip/hip_runtime.h>
#include <math.h>

// ToxicityGATv2 — round 11: r9 proven body (VGPR=64, 8 waves/SIMD) with the
// agg_csr softmax reduce switched from ds_swizzle (__shfl_xor, LDS pipe,
// lgkmcnt-coupled) to DPP row_ror rotate-reduce (pure VALU, zero VGPR cost).
// Round-10's deep-ILP variant reverted: it crossed the 64-VGPR occupancy
// cliff (8->4 waves/SIMD) and lost more TLP than the ILP gained.

constexpr int N_ = 50000;
constexpr int E_ = 400000;
constexpr int G_ = 2000;
constexpr int H_ = 128;
constexpr int IN_ = 39;

typedef __attribute__((ext_vector_type(8))) short bf16x8;
typedef __attribute__((ext_vector_type(4))) float f32x4;

// ---------------- bf16 pack/unpack (RNE) ----------------
__device__ __forceinline__ unsigned pk_bf16(float a, float b) {
  unsigned ua = __float_as_uint(a);
  unsigned ub = __float_as_uint(b);
  ua = (ua + 0x7fffu + ((ua >> 16) & 1u)) >> 16;
  ub = (ub + 0x7fffu + ((ub >> 16) & 1u)) & 0xffff0000u;
  return ua | ub;
}
__device__ __forceinline__ unsigned short bf16_1(float x) {
  unsigned u = __float_as_uint(x);
  u = (u + 0x7fffu + ((u >> 16) & 1u)) >> 16;
  return (unsigned short)u;
}
__device__ __forceinline__ float up_lo(unsigned u) { return __uint_as_float(u << 16); }
__device__ __forceinline__ float up_hi(unsigned u) { return __uint_as_float(u & 0xffff0000u); }

// ---------------- DPP rotate-reduce over 16-lane rows (VALU pipe, no LDS) ----
template <int CTRL>
__device__ __forceinline__ float dpp_radd(float x) {
  int y = __builtin_amdgcn_update_dpp(0, __float_as_int(x), CTRL, 0xF, 0xF, false);
  return x + __int_as_float(y);
}
__device__ __forceinline__ float row_reduce16(float p) {
  p = dpp_radd<0x121>(p);  // row_ror:1
  p = dpp_radd<0x122>(p);  // row_ror:2
  p = dpp_radd<0x124>(p);  // row_ror:4
  p = dpp_radd<0x128>(p);  // row_ror:8
  return p;
}

// ---------------- histogram ----------------
__global__ __launch_bounds__(256) void hist_kernel(const int* __restrict__ keys, int n,
                                                   int* __restrict__ cnt) {
  for (int i = blockIdx.x * 256 + threadIdx.x; i < n; i += gridDim.x * 256)
    atomicAdd(&cnt[keys[i]], 1);
}

// ---------------- multi-block scan ----------------
__global__ __launch_bounds__(1024) void scan_local(const int* __restrict__ in,
                                                   int* __restrict__ outx,
                                                   int* __restrict__ bsum, int n) {
  __shared__ int wsum[16];
  int t = threadIdx.x, lane = t & 63, wid = t >> 6;
  int idx = blockIdx.x * 1024 + t;
  int v = (idx < n) ? in[idx] : 0;
  int x = v;
#pragma unroll
  for (int off = 1; off < 64; off <<= 1) {
    int y = __shfl_up(x, off, 64);
    if (lane >= off) x += y;
  }
  if (lane == 63) wsum[wid] = x;
  __syncthreads();
  if (t == 0) {
    int acc = 0;
#pragma unroll
    for (int w = 0; w < 16; w++) { int tmp = wsum[w]; wsum[w] = acc; acc += tmp; }
    bsum[blockIdx.x] = acc;
  }
  __syncthreads();
  if (idx < n) outx[idx] = wsum[wid] + x - v;
}

__global__ __launch_bounds__(64) void scan_bsum(const int* __restrict__ bsum,
                                                int* __restrict__ boff, int nb) {
  int t = threadIdx.x;
  int v = (t < nb) ? bsum[t] : 0;
  int x = v;
#pragma unroll
  for (int off = 1; off < 64; off <<= 1) {
    int y = __shfl_up(x, off, 64);
    if (t >= off) x += y;
  }
  boff[t] = x - v;
}

__global__ __launch_bounds__(1024) void scan_add(int* __restrict__ eoff,
                                                 const int* __restrict__ boff,
                                                 int* __restrict__ cursor, int n) {
  int idx = blockIdx.x * 1024 + threadIdx.x;
  if (idx < n) {
    int e = eoff[idx] + boff[idx >> 10];
    eoff[idx] = e;
    cursor[idx] = e;
  }
  if (idx == 0) eoff[n] = E_;
}

// ---------------- goff from sorted batch ----------------
__global__ __launch_bounds__(256) void goff_from_sorted(const int* __restrict__ batch,
                                                        int* __restrict__ goff) {
  int i = blockIdx.x * 256 + threadIdx.x;
  if (i >= N_) return;
  int bi = batch[i];
  int bp = (i == 0) ? -1 : batch[i - 1];
  for (int g = bp + 1; g <= bi; g++) goff[g] = i;
  if (i == N_ - 1) {
    for (int g = bi + 1; g <= G_; g++) goff[g] = N_;
  }
}

// ---------------- edge scatter (bf16 attrs) ----------------
__global__ __launch_bounds__(256) void edge_scatter(const int* __restrict__ ei,
                                                    const float* __restrict__ ea,
                                                    int* __restrict__ cursor,
                                                    int* __restrict__ esrc,
                                                    unsigned* __restrict__ easb) {
  int e = blockIdx.x * 256 + threadIdx.x;
  if (e >= E_) return;
  int src = ei[e];
  int dst = ei[E_ + e];
  int j = atomicAdd(&cursor[dst], 1);
  esrc[j] = src;
  const float4* eav = (const float4*)(ea + (size_t)e * 8);
  float4 a0 = eav[0], a1 = eav[1];
  uint4 o;
  o.x = pk_bf16(a0.x, a0.y);
  o.y = pk_bf16(a0.z, a0.w);
  o.z = pk_bf16(a1.x, a1.y);
  o.w = pk_bf16(a1.z, a1.w);
  ((uint4*)easb)[j] = o;
}

// ---------------- weight pre-pack: wpack[l][n][k] = bf16([Wl|Wr][k][n]) -------
__global__ __launch_bounds__(256) void pack_weights(const float* __restrict__ Wl,
                                                    const float* __restrict__ Wr,
                                                    unsigned short* __restrict__ wpack) {
  int i = blockIdx.x * 256 + threadIdx.x;  // enumerate (l, k, n) read-coalesced
  if (i >= 3 * 128 * 256) return;
  int l = i >> 15;
  int rem = i & 32767;
  int k = rem >> 8;
  int n = rem & 255;
  const float* Wsrc = (n < 128) ? (Wl + l * H_ * H_) : (Wr + l * H_ * H_);
  int nn = n & 127;
  wpack[(size_t)l * 32768 + n * 128 + k] = bf16_1(Wsrc[k * H_ + nn]);
}

// ---------------- input GEMM + fused colstats ----------------
__global__ __launch_bounds__(256) void in_gemm(const float* __restrict__ x,
                                               const float* __restrict__ W,
                                               const float* __restrict__ b,
                                               float* __restrict__ y,
                                               float* __restrict__ ssum,
                                               float* __restrict__ ssq) {
  __shared__ float xs[32][40];
  __shared__ float s1[256], s2[256];
  int t = threadIdx.x;
  int row0 = blockIdx.x * 32;
  for (int i = t; i < 32 * IN_; i += 256) {
    int r = i / IN_, k = i % IN_;
    int row = row0 + r;
    xs[r][k] = (row < N_) ? x[row * IN_ + k] : 0.f;
  }
  __syncthreads();
  int col = t & 127;
  int half = t >> 7;
  float acc[16];
#pragma unroll
  for (int r = 0; r < 16; r++) acc[r] = 0.f;
  for (int k = 0; k < IN_; k++) {
    float w = W[k * H_ + col];
#pragma unroll
    for (int r = 0; r < 16; r++) acc[r] = fmaf(xs[half * 16 + r][k], w, acc[r]);
  }
  float bb = b[col];
  float a1 = 0.f, a2 = 0.f;
#pragma unroll
  for (int r = 0; r < 16; r++) {
    int row = row0 + half * 16 + r;
    float v = acc[r] + bb;
    if (row < N_) {
      y[row * H_ + col] = v;
      a1 += v;
      a2 = fmaf(v, v, a2);
    }
  }
  s1[t] = a1; s2[t] = a2;
  __syncthreads();
  if (t < 128) {
    atomicAdd(&ssum[t], s1[t] + s1[t + 128]);
    atomicAdd(&ssq[t], s2[t] + s2[t + 128]);
  }
}

// ---------------- MFMA node GEMM (pre-packed bf16 B) ----------
// MODE 1: v=relu(bn(buf)); xn=v.  MODE 2: v=xn+elu(bn(buf)); xn=v.
template <int MODE>
__global__ __launch_bounds__(256) void gemm_mfma(float* __restrict__ xn,
                                                 const float* __restrict__ buf,
                                                 const float* __restrict__ g,
                                                 const float* __restrict__ beta,
                                                 const float* __restrict__ ssum,
                                                 const float* __restrict__ ssq,
                                                 float rows_inv,
                                                 const unsigned short* __restrict__ wp,
                                                 unsigned* __restrict__ xlb,
                                                 unsigned* __restrict__ xrb) {
  __shared__ char smem[17408 + 20480];
  short (*a_s)[136] = (short(*)[136])smem;              // 64 rows x 128 k (pad 136)
  short (*b_s)[40] = (short(*)[40])(smem + 17408);      // 256 n x 32 k (pad 40)
  float* t2base = (float*)(smem + 17408);               // epilogue reuse
  int t = threadIdx.x;
  int lane = t & 63, w = t >> 6;
  int quad = lane >> 4, lc = lane & 15;
  int row0 = blockIdx.x * 64;

  // ---- stage A (fused BN epilogue, fp32 xn updated, bf16 into LDS) ----
  {
    int r = t >> 2;
    int row = row0 + r;
    int kb0 = (t & 3) * 32;
    bool valid = row < N_;
    for (int kk = 0; kk < 32; kk += 4) {
      int c = kb0 + kk;
      float4 v = make_float4(0.f, 0.f, 0.f, 0.f);
      if (valid) {
        float4 bv = *(const float4*)&buf[(size_t)row * H_ + c];
        float4 gv = *(const float4*)&g[c];
        float4 be = *(const float4*)&beta[c];
        float4 s1 = *(const float4*)&ssum[c];
        float4 s2 = *(const float4*)&ssq[c];
        float m0 = s1.x * rows_inv, m1 = s1.y * rows_inv, m2 = s1.z * rows_inv, m3 = s1.w * rows_inv;
        float r0 = rsqrtf(s2.x * rows_inv - m0 * m0 + 1e-5f);
        float r1 = rsqrtf(s2.y * rows_inv - m1 * m1 + 1e-5f);
        float r2 = rsqrtf(s2.z * rows_inv - m2 * m2 + 1e-5f);
        float r3 = rsqrtf(s2.w * rows_inv - m3 * m3 + 1e-5f);
        float t0 = gv.x * (bv.x - m0) * r0 + be.x;
        float t1 = gv.y * (bv.y - m1) * r1 + be.y;
        float t2 = gv.z * (bv.z - m2) * r2 + be.z;
        float t3 = gv.w * (bv.w - m3) * r3 + be.w;
        if (MODE == 1) {
          v = make_float4(fmaxf(t0, 0.f), fmaxf(t1, 0.f), fmaxf(t2, 0.f), fmaxf(t3, 0.f));
        } else {
          float4 xo = *(const float4*)&xn[(size_t)row * H_ + c];
          v.x = xo.x + ((t0 > 0.f) ? t0 : (__expf(t0) - 1.f));
          v.y = xo.y + ((t1 > 0.f) ? t1 : (__expf(t1) - 1.f));
          v.z = xo.z + ((t2 > 0.f) ? t2 : (__expf(t2) - 1.f));
          v.w = xo.w + ((t3 > 0.f) ? t3 : (__expf(t3) - 1.f));
        }
        *(float4*)&xn[(size_t)row * H_ + c] = v;
      }
      uint2 pk;
      pk.x = pk_bf16(v.x, v.y);
      pk.y = pk_bf16(v.z, v.w);
      *(uint2*)&a_s[r][c] = pk;
    }
  }

  f32x4 acc[16];
#pragma unroll
  for (int nt = 0; nt < 16; nt++) acc[nt] = (f32x4){0.f, 0.f, 0.f, 0.f};

  for (int kb = 0; kb < 4; kb++) {
    __syncthreads();
    // stage B chunk: vectorized copy from pre-packed weights (16 KB)
    for (int i = t; i < 1024; i += 256) {
      int n = i >> 2;
      int k8 = (i & 3) * 8;
      *(uint4*)&b_s[n][k8] = *(const uint4*)&wp[(size_t)n * 128 + kb * 32 + k8];
    }
    __syncthreads();
    bf16x8 av = *(const bf16x8*)&a_s[w * 16 + lc][kb * 32 + quad * 8];
#pragma unroll
    for (int nt = 0; nt < 16; nt++) {
      bf16x8 bv = *(const bf16x8*)&b_s[nt * 16 + lc][quad * 8];
      acc[nt] = __builtin_amdgcn_mfma_f32_16x16x32_bf16(av, bv, acc[nt], 0, 0, 0);
    }
  }
  __syncthreads();  // b_s -> t2 reuse

  // ---- epilogue: transpose 16x32 chunks via LDS, packed coalesced stores ----
  float* t2 = t2base + w * 544;  // 16 rows x 34 cols fp32, per-wave private
  for (int ntp = 0; ntp < 8; ntp++) {
#pragma unroll
    for (int rr = 0; rr < 4; rr++) {
      t2[(quad * 4 + rr) * 34 + lc] = acc[2 * ntp][rr];
      t2[(quad * 4 + rr) * 34 + 16 + lc] = acc[2 * ntp + 1][rr];
    }
    __asm__ volatile("s_waitcnt lgkmcnt(0)" ::: "memory");
#pragma unroll
    for (int it = 0; it < 4; it++) {
      int item = lane + it * 64;
      int p = item & 15, rowi = item >> 4;
      float v0 = t2[rowi * 34 + 2 * p];
      float v1 = t2[rowi * 34 + 2 * p + 1];
      unsigned u = pk_bf16(v0, v1);
      int colpair = ntp * 16 + p;
      int rowg = row0 + w * 16 + rowi;
      if (rowg < N_) {
        if (colpair < 64) xlb[(size_t)rowg * 64 + colpair] = u;
        else xrb[(size_t)rowg * 64 + colpair - 64] = u;
      }
    }
    __asm__ volatile("s_waitcnt lgkmcnt(0)" ::: "memory");
  }
}

// ---------------- CSR aggregation (r9 body + DPP reduce) ----------------
__device__ __forceinline__ float ep8u(const uint4& u, const float* w) {
  float ep = up_lo(u.x) * w[0];
  ep = fmaf(up_hi(u.x), w[1], ep);
  ep = fmaf(up_lo(u.y), w[2], ep);
  ep = fmaf(up_hi(u.y), w[3], ep);
  ep = fmaf(up_lo(u.z), w[4], ep);
  ep = fmaf(up_hi(u.z), w[5], ep);
  ep = fmaf(up_lo(u.w), w[6], ep);
  ep = fmaf(up_hi(u.w), w[7], ep);
  return ep;
}

__global__ __launch_bounds__(256) void agg_csr(const int* __restrict__ eoff,
                                               const int* __restrict__ esrc,
                                               const unsigned* __restrict__ easb,
                                               const float* __restrict__ Wel,
                                               const float* __restrict__ attl,
                                               const unsigned* __restrict__ xlb,
                                               const unsigned* __restrict__ xrb,
                                               const float* __restrict__ cb,
                                               float* __restrict__ buf,
                                               float* __restrict__ ssum,
                                               float* __restrict__ ssq) {
  __shared__ float sA[256], sB[256], sC[256], sD[256];
  int t = threadIdx.x;
  int l = t & 63;
  int sub = t >> 6;
  int c0 = l * 2;
  float w0[8], w1[8];
#pragma unroll
  for (int k = 0; k < 8; k++) {
    float2 wv = *(const float2*)&Wel[k * H_ + c0];
    w0[k] = wv.x; w1[k] = wv.y;
  }
  float2 attv = *(const float2*)&attl[c0];
  float2 cbv = *(const float2*)&cb[c0];
  const uint4* eas4 = (const uint4*)easb;
  float a1_0 = 0.f, a1_1 = 0.f, a2_0 = 0.f, a2_1 = 0.f;
  for (int n = blockIdx.x * 4 + sub; n < N_; n += gridDim.x * 4) {
    unsigned xru = xrb[(size_t)n * 64 + l];
    float xr0 = up_lo(xru), xr1 = up_hi(xru);
    int e0 = eoff[n], e1 = eoff[n + 1];
    float acc0 = 0.f, acc1 = 0.f, den = 0.f;
    int j = e0;
    for (; j + 4 <= e1; j += 4) {
      int s0 = esrc[j], s1 = esrc[j + 1], s2 = esrc[j + 2], s3 = esrc[j + 3];
      uint4 u0 = eas4[j], u1 = eas4[j + 1], u2 = eas4[j + 2], u3 = eas4[j + 3];
      unsigned xu0 = xlb[(size_t)s0 * 64 + l];
      unsigned xu1 = xlb[(size_t)s1 * 64 + l];
      unsigned xu2 = xlb[(size_t)s2 * 64 + l];
      unsigned xu3 = xlb[(size_t)s3 * 64 + l];
      float x00 = up_lo(xu0), x01 = up_hi(xu0);
      float x10 = up_lo(xu1), x11 = up_hi(xu1);
      float x20 = up_lo(xu2), x21 = up_hi(xu2);
      float x30 = up_lo(xu3), x31 = up_hi(xu3);
      float m00 = x00 + xr0 + ep8u(u0, w0);
      float m01 = x01 + xr1 + ep8u(u0, w1);
      float m10 = x10 + xr0 + ep8u(u1, w0);
      float m11 = x11 + xr1 + ep8u(u1, w1);
      float m20 = x20 + xr0 + ep8u(u2, w0);
      float m21 = x21 + xr1 + ep8u(u2, w1);
      float m30 = x30 + xr0 + ep8u(u3, w0);
      float m31 = x31 + xr1 + ep8u(u3, w1);
      m00 = (m00 > 0.f) ? m00 : 0.2f * m00;
      m01 = (m01 > 0.f) ? m01 : 0.2f * m01;
      m10 = (m10 > 0.f) ? m10 : 0.2f * m10;
      m11 = (m11 > 0.f) ? m11 : 0.2f * m11;
      m20 = (m20 > 0.f) ? m20 : 0.2f * m20;
      m21 = (m21 > 0.f) ? m21 : 0.2f * m21;
      m30 = (m30 > 0.f) ? m30 : 0.2f * m30;
      m31 = (m31 > 0.f) ? m31 : 0.2f * m31;
      float p0 = fmaf(m00, attv.x, m01 * attv.y);
      float p1 = fmaf(m10, attv.x, m11 * attv.y);
      float p2 = fmaf(m20, attv.x, m21 * attv.y);
      float p3 = fmaf(m30, attv.x, m31 * attv.y);
      p0 = row_reduce16(p0);
      p1 = row_reduce16(p1);
      p2 = row_reduce16(p2);
      p3 = row_reduce16(p3);
      float e0v = __expf(p0), e1v = __expf(p1), e2v = __expf(p2), e3v = __expf(p3);
      acc0 = fmaf(e0v, x00, acc0); acc1 = fmaf(e0v, x01, acc1);
      acc0 = fmaf(e1v, x10, acc0); acc1 = fmaf(e1v, x11, acc1);
      acc0 = fmaf(e2v, x20, acc0); acc1 = fmaf(e2v, x21, acc1);
      acc0 = fmaf(e3v, x30, acc0); acc1 = fmaf(e3v, x31, acc1);
      den += (e0v + e1v) + (e2v + e3v);
    }
    for (; j < e1; j++) {
      int s0 = esrc[j];
      uint4 u0 = eas4[j];
      unsigned xu0 = xlb[(size_t)s0 * 64 + l];
      float x00 = up_lo(xu0), x01 = up_hi(xu0);
      float m00 = x00 + xr0 + ep8u(u0, w0);
      float m01 = x01 + xr1 + ep8u(u0, w1);
      m00 = (m00 > 0.f) ? m00 : 0.2f * m00;
      m01 = (m01 > 0.f) ? m01 : 0.2f * m01;
      float p0 = fmaf(m00, attv.x, m01 * attv.y);
      p0 = row_reduce16(p0);
      float e0v = __expf(p0);
      acc0 = fmaf(e0v, x00, acc0);
      acc1 = fmaf(e0v, x01, acc1);
      den += e0v;
    }
    float inv = 1.f / (den + 1e-16f);
    float h0 = acc0 * inv + cbv.x;
    float h1 = acc1 * inv + cbv.y;
    *(float2*)&buf[(size_t)n * H_ + c0] = make_float2(h0, h1);
    a1_0 += h0; a1_1 += h1;
    a2_0 = fmaf(h0, h0, a2_0); a2_1 = fmaf(h1, h1, a2_1);
  }
  sA[t] = a1_0; sB[t] = a1_1; sC[t] = a2_0; sD[t] = a2_1;
  __syncthreads();
  if (t < 64) {
    float r1 = sA[t] + sA[t + 64] + sA[t + 128] + sA[t + 192];
    float r2 = sB[t] + sB[t + 64] + sB[t + 128] + sB[t + 192];
    float r3 = sC[t] + sC[t + 64] + sC[t + 128] + sC[t + 192];
    float r4 = sD[t] + sD[t + 64] + sD[t + 128] + sD[t + 192];
    atomicAdd(&ssum[2 * t], r1);
    atomicAdd(&ssum[2 * t + 1], r2);
    atomicAdd(&ssq[2 * t], r3);
    atomicAdd(&ssq[2 * t + 1], r4);
  }
}

// ---------------- BN apply with inline finalize ----------------
__global__ __launch_bounds__(256) void apply_bn_relu(const float* __restrict__ y,
                                                     float* __restrict__ out,
                                                     const float* __restrict__ g,
                                                     const float* __restrict__ beta,
                                                     const float* __restrict__ ssum,
                                                     const float* __restrict__ ssq,
                                                     float rows_inv,
                                                     long total, int cmask) {
  long i = (long)blockIdx.x * 256 + threadIdx.x;
  if (i >= total) return;
  int c = (int)i & cmask;
  float m = ssum[c] * rows_inv;
  float rs = rsqrtf(ssq[c] * rows_inv - m * m + 1e-5f);
  float v = g[c] * (y[i] - m) * rs + beta[c];
  out[i] = fmaxf(v, 0.f);
}

// ---------------- pooling with fused layer-2 residual (inline BN finalize) ----
__global__ __launch_bounds__(128) void pool_residual(const int* __restrict__ goff,
                                                     const float* __restrict__ xn,
                                                     const float* __restrict__ buf,
                                                     const float* __restrict__ g,
                                                     const float* __restrict__ beta,
                                                     const float* __restrict__ ssum,
                                                     const float* __restrict__ ssq,
                                                     float rows_inv,
                                                     float* __restrict__ xg) {
  int gr = blockIdx.x;
  int t = threadIdx.x;
  int n0 = goff[gr], n1 = goff[gr + 1];
  float mm = ssum[t] * rows_inv;
  float rr = rsqrtf(ssq[t] * rows_inv - mm * mm + 1e-5f);
  float gg = g[t], bb = beta[t];
  float s = 0.f, mx = -INFINITY;
  for (int n = n0; n < n1; n++) {
    float w = gg * (buf[(size_t)n * H_ + t] - mm) * rr + bb;
    w = (w > 0.f) ? w : (__expf(w) - 1.f);
    float v = xn[(size_t)n * H_ + t] + w;
    s += v;
    mx = fmaxf(mx, v);
  }
  float c = (float)(n1 - n0);
  xg[gr * 384 + t] = s / fmaxf(c, 1.f);
  xg[gr * 384 + 128 + t] = (c > 0.f) ? mx : 0.f;
  xg[gr * 384 + 256 + t] = s;
}

// ---------------- MLP GEMMs (fused colstats) ----------------
template <int K, int COLS>
__global__ void mlp_gemm(const float* __restrict__ A, const float* __restrict__ W,
                         const float* __restrict__ b, float* __restrict__ Y, int rows,
                         float* __restrict__ ssum, float* __restrict__ ssq) {
  __shared__ float xs[8][K];
  int t = threadIdx.x;
  int row0 = blockIdx.x * 8;
  for (int i = t; i < 8 * K; i += COLS) {
    int r = i / K, k = i % K;
    int row = row0 + r;
    xs[r][k] = (row < rows) ? A[row * K + k] : 0.f;
  }
  __syncthreads();
  float acc[8];
#pragma unroll
  for (int r = 0; r < 8; r++) acc[r] = 0.f;
  for (int k = 0; k < K; k++) {
    float w = W[k * COLS + t];
#pragma unroll
    for (int r = 0; r < 8; r++) acc[r] = fmaf(xs[r][k], w, acc[r]);
  }
  float bb = b[t];
  float a1 = 0.f, a2 = 0.f;
#pragma unroll
  for (int r = 0; r < 8; r++) {
    int row = row0 + r;
    if (row < rows) {
      float v = acc[r] + bb;
      Y[row * COLS + t] = v;
      a1 += v;
      a2 = fmaf(v, v, a2);
    }
  }
  atomicAdd(&ssum[t], a1);
  atomicAdd(&ssq[t], a2);
}

// ---------------- head ----------------
__global__ __launch_bounds__(64) void head_kernel(const float* __restrict__ u,
                                                  const float* __restrict__ W,
                                                  const float* __restrict__ b,
                                                  float* __restrict__ out) {
  __shared__ float row[128];
  int g = blockIdx.x;
  int t = threadIdx.x;
  row[t] = u[g * 128 + t];
  row[t + 64] = u[g * 128 + 64 + t];
  __syncthreads();
  if (t < 12) {
    float acc = b[t];
    for (int k = 0; k < 128; k++) acc = fmaf(row[k], W[k * 12 + t], acc);
    out[g * 12 + t] = 1.f / (1.f + expf(-acc));
  }
}

// ---------------- launcher ----------------
extern "C" void kernel_launch(void* const* d_in, const int* in_sizes, int n_in, void* d_out,
                              int out_size, void* d_ws, size_t ws_size, hipStream_t stream) {
  (void)in_sizes; (void)n_in; (void)out_size; (void)ws_size;
  const float* x       = (const float*)d_in[0];
  const int*   ei      = (const int*)d_in[1];
  const float* ea      = (const float*)d_in[2];
  const int*   batch   = (const int*)d_in[3];
  const float* in_W    = (const float*)d_in[4];
  const float* in_b    = (const float*)d_in[5];
  const float* in_g    = (const float*)d_in[6];
  const float* in_beta = (const float*)d_in[7];
  const float* Wl      = (const float*)d_in[8];
  const float* Wr      = (const float*)d_in[9];
  const float* We      = (const float*)d_in[10];
  const float* att     = (const float*)d_in[11];
  const float* conv_b  = (const float*)d_in[12];
  const float* bn_g    = (const float*)d_in[13];
  const float* bn_b    = (const float*)d_in[14];
  const float* t1_W    = (const float*)d_in[15];
  const float* t1_b    = (const float*)d_in[16];
  const float* t1_g    = (const float*)d_in[17];
  const float* t1_beta = (const float*)d_in[18];
  const float* t2_W    = (const float*)d_in[19];
  const float* t2_b    = (const float*)d_in[20];
  const float* t2_g    = (const float*)d_in[21];
  const float* t2_beta = (const float*)d_in[22];
  const float* head_W  = (const float*)d_in[23];
  const float* head_b  = (const float*)d_in[24];
  float* out = (float*)d_out;

  float* p = (float*)d_ws;
  float* xn    = p; p += N_ * H_;
  float* buf   = p; p += N_ * H_;
  float* sstat = p; p += 6 * 512;   // 6 stages x (ssum 256 | ssq 256)
  float* xg    = p; p += G_ * 384;
  float* u1    = p; p += G_ * 256;
  float* u2    = p; p += G_ * 128;
  unsigned* up = (unsigned*)p;
  unsigned* xlb  = up; up += (size_t)N_ * 64;
  unsigned* xrb  = up; up += (size_t)N_ * 64;
  unsigned* easb = up; up += (size_t)E_ * 4;
  unsigned short* wpack = (unsigned short*)up; up += 3 * 32768 / 2;
  int* ip = (int*)up;
  int* deg    = ip; ip += N_;
  int* eoff   = ip; ip += N_ + 1;
  int* cursor = ip; ip += N_;
  int* goff   = ip; ip += G_ + 1;
  int* esrc   = ip; ip += E_;
  int* bsum   = ip; ip += 64;
  int* boff   = ip; ip += 64;

#define SSUM(s) (sstat + (s) * 512)
#define SSQ(s)  (sstat + (s) * 512 + 256)

  // ---- build CSR structures + pre-pack weights ----
  hipMemsetAsync(deg, 0, (size_t)N_ * sizeof(int), stream);
  hipMemsetAsync(sstat, 0, 6 * 512 * sizeof(float), stream);
  hist_kernel<<<1024, 256, 0, stream>>>(ei + E_, E_, deg);
  scan_local<<<49, 1024, 0, stream>>>(deg, eoff, bsum, N_);
  scan_bsum<<<1, 64, 0, stream>>>(bsum, boff, 49);
  scan_add<<<49, 1024, 0, stream>>>(eoff, boff, cursor, N_);
  edge_scatter<<<(E_ + 255) / 256, 256, 0, stream>>>(ei, ea, cursor, esrc, easb);
  goff_from_sorted<<<(N_ + 255) / 256, 256, 0, stream>>>(batch, goff);
  pack_weights<<<384, 256, 0, stream>>>(Wl, Wr, wpack);

  // ---- input layer (stats -> stage 0) ----
  in_gemm<<<(N_ + 31) / 32, 256, 0, stream>>>(x, in_W, in_b, buf, SSUM(0), SSQ(0));

  // ---- 3 GATv2 layers (conv stats of layer l -> stage l+1) ----
  const float rnInv = 1.f / N_;
  for (int l = 0; l < 3; l++) {
    if (l == 0) {
      gemm_mfma<1><<<782, 256, 0, stream>>>(xn, buf, in_g, in_beta, SSUM(0), SSQ(0), rnInv,
                                            wpack + (size_t)l * 32768, xlb, xrb);
    } else {
      gemm_mfma<2><<<782, 256, 0, stream>>>(xn, buf, bn_g + (l - 1) * H_, bn_b + (l - 1) * H_,
                                            SSUM(l), SSQ(l), rnInv,
                                            wpack + (size_t)l * 32768, xlb, xrb);
    }
    agg_csr<<<2048, 256, 0, stream>>>(eoff, esrc, easb, We + l * 8 * H_, att + l * H_,
                                      xlb, xrb, conv_b + l * H_, buf, SSUM(l + 1), SSQ(l + 1));
  }

  // ---- pooling with fused layer-2 residual (stage 3 stats) ----
  pool_residual<<<G_, 128, 0, stream>>>(goff, xn, buf, bn_g + 2 * H_, bn_b + 2 * H_,
                                        SSUM(3), SSQ(3), rnInv, xg);

  // ---- t1 (stats -> stage 4) ----
  const float rgInv = 1.f / G_;
  mlp_gemm<384, 256><<<G_ / 8, 256, 0, stream>>>(xg, t1_W, t1_b, u1, G_, SSUM(4), SSQ(4));
  apply_bn_relu<<<(G_ * 256 + 255) / 256, 256, 0, stream>>>(u1, u1, t1_g, t1_beta,
                                                            SSUM(4), SSQ(4), rgInv,
                                                            (long)G_ * 256, 255);

  // ---- t2 (stats -> stage 5) ----
  mlp_gemm<256, 128><<<G_ / 8, 128, 0, stream>>>(u1, t2_W, t2_b, u2, G_, SSUM(5), SSQ(5));
  apply_bn_relu<<<(G_ * 128 + 255) / 256, 256, 0, stream>>>(u2, u2, t2_g, t2_beta,
                                                            SSUM(5), SSQ(5), rgInv,
                                                            (long)G_ * 128, 127);

  // ---- head ----
  head_kernel<<<G_, 64, 0, stream>>>(u2, head_W, head_b, out);
#undef SSUM
#undef SSQ
}

// Round 3
// 852.153 us; speedup vs baseline: 1.0228x; 1.0017x over previous
//
#include <hip/hip_runtime.h>
#include <math.h>

// ToxicityGATv2 — round 12: r11 body (DPP reduce, VGPR<=64) + register-cheap
// latency cuts in agg_csr:
//  * esrc preloaded once per 64-edge chunk into a lane register; per-pack
//    sources via readlane -> SGPR (kills the per-pack esrc load+waitcnt,
//    makes eas4 addresses wave-uniform/scalarizable)
//  * masked 4-pack tail replaces the serial per-edge remainder loop
//    (~1.5 full-latency chains per node removed)
// r10's W=8 + deep pipeline stays reverted (VGPR cliff at 64).

constexpr int N_ = 50000;
constexpr int E_ = 400000;
constexpr int G_ = 2000;
constexpr int H_ = 128;
constexpr int IN_ = 39;

typedef __attribute__((ext_vector_type(8))) short bf16x8;
typedef __attribute__((ext_vector_type(4))) float f32x4;

// ---------------- bf16 pack/unpack (RNE) ----------------
__device__ __forceinline__ unsigned pk_bf16(float a, float b) {
  unsigned ua = __float_as_uint(a);
  unsigned ub = __float_as_uint(b);
  ua = (ua + 0x7fffu + ((ua >> 16) & 1u)) >> 16;
  ub = (ub + 0x7fffu + ((ub >> 16) & 1u)) & 0xffff0000u;
  return ua | ub;
}
__device__ __forceinline__ unsigned short bf16_1(float x) {
  unsigned u = __float_as_uint(x);
  u = (u + 0x7fffu + ((u >> 16) & 1u)) >> 16;
  return (unsigned short)u;
}
__device__ __forceinline__ float up_lo(unsigned u) { return __uint_as_float(u << 16); }
__device__ __forceinline__ float up_hi(unsigned u) { return __uint_as_float(u & 0xffff0000u); }

// ---------------- DPP rotate-reduce over 16-lane rows (VALU pipe, no LDS) ----
template <int CTRL>
__device__ __forceinline__ float dpp_radd(float x) {
  int y = __builtin_amdgcn_update_dpp(0, __float_as_int(x), CTRL, 0xF, 0xF, false);
  return x + __int_as_float(y);
}
__device__ __forceinline__ float row_reduce16(float p) {
  p = dpp_radd<0x121>(p);  // row_ror:1
  p = dpp_radd<0x122>(p);  // row_ror:2
  p = dpp_radd<0x124>(p);  // row_ror:4
  p = dpp_radd<0x128>(p);  // row_ror:8
  return p;
}

// ---------------- histogram ----------------
__global__ __launch_bounds__(256) void hist_kernel(const int* __restrict__ keys, int n,
                                                   int* __restrict__ cnt) {
  for (int i = blockIdx.x * 256 + threadIdx.x; i < n; i += gridDim.x * 256)
    atomicAdd(&cnt[keys[i]], 1);
}

// ---------------- multi-block scan ----------------
__global__ __launch_bounds__(1024) void scan_local(const int* __restrict__ in,
                                                   int* __restrict__ outx,
                                                   int* __restrict__ bsum, int n) {
  __shared__ int wsum[16];
  int t = threadIdx.x, lane = t & 63, wid = t >> 6;
  int idx = blockIdx.x * 1024 + t;
  int v = (idx < n) ? in[idx] : 0;
  int x = v;
#pragma unroll
  for (int off = 1; off < 64; off <<= 1) {
    int y = __shfl_up(x, off, 64);
    if (lane >= off) x += y;
  }
  if (lane == 63) wsum[wid] = x;
  __syncthreads();
  if (t == 0) {
    int acc = 0;
#pragma unroll
    for (int w = 0; w < 16; w++) { int tmp = wsum[w]; wsum[w] = acc; acc += tmp; }
    bsum[blockIdx.x] = acc;
  }
  __syncthreads();
  if (idx < n) outx[idx] = wsum[wid] + x - v;
}

__global__ __launch_bounds__(64) void scan_bsum(const int* __restrict__ bsum,
                                                int* __restrict__ boff, int nb) {
  int t = threadIdx.x;
  int v = (t < nb) ? bsum[t] : 0;
  int x = v;
#pragma unroll
  for (int off = 1; off < 64; off <<= 1) {
    int y = __shfl_up(x, off, 64);
    if (t >= off) x += y;
  }
  boff[t] = x - v;
}

__global__ __launch_bounds__(1024) void scan_add(int* __restrict__ eoff,
                                                 const int* __restrict__ boff,
                                                 int* __restrict__ cursor, int n) {
  int idx = blockIdx.x * 1024 + threadIdx.x;
  if (idx < n) {
    int e = eoff[idx] + boff[idx >> 10];
    eoff[idx] = e;
    cursor[idx] = e;
  }
  if (idx == 0) eoff[n] = E_;
}

// ---------------- goff from sorted batch ----------------
__global__ __launch_bounds__(256) void goff_from_sorted(const int* __restrict__ batch,
                                                        int* __restrict__ goff) {
  int i = blockIdx.x * 256 + threadIdx.x;
  if (i >= N_) return;
  int bi = batch[i];
  int bp = (i == 0) ? -1 : batch[i - 1];
  for (int g = bp + 1; g <= bi; g++) goff[g] = i;
  if (i == N_ - 1) {
    for (int g = bi + 1; g <= G_; g++) goff[g] = N_;
  }
}

// ---------------- edge scatter (bf16 attrs) ----------------
__global__ __launch_bounds__(256) void edge_scatter(const int* __restrict__ ei,
                                                    const float* __restrict__ ea,
                                                    int* __restrict__ cursor,
                                                    int* __restrict__ esrc,
                                                    unsigned* __restrict__ easb) {
  int e = blockIdx.x * 256 + threadIdx.x;
  if (e >= E_) return;
  int src = ei[e];
  int dst = ei[E_ + e];
  int j = atomicAdd(&cursor[dst], 1);
  esrc[j] = src;
  const float4* eav = (const float4*)(ea + (size_t)e * 8);
  float4 a0 = eav[0], a1 = eav[1];
  uint4 o;
  o.x = pk_bf16(a0.x, a0.y);
  o.y = pk_bf16(a0.z, a0.w);
  o.z = pk_bf16(a1.x, a1.y);
  o.w = pk_bf16(a1.z, a1.w);
  ((uint4*)easb)[j] = o;
}

// ---------------- weight pre-pack: wpack[l][n][k] = bf16([Wl|Wr][k][n]) -------
__global__ __launch_bounds__(256) void pack_weights(const float* __restrict__ Wl,
                                                    const float* __restrict__ Wr,
                                                    unsigned short* __restrict__ wpack) {
  int i = blockIdx.x * 256 + threadIdx.x;  // enumerate (l, k, n) read-coalesced
  if (i >= 3 * 128 * 256) return;
  int l = i >> 15;
  int rem = i & 32767;
  int k = rem >> 8;
  int n = rem & 255;
  const float* Wsrc = (n < 128) ? (Wl + l * H_ * H_) : (Wr + l * H_ * H_);
  int nn = n & 127;
  wpack[(size_t)l * 32768 + n * 128 + k] = bf16_1(Wsrc[k * H_ + nn]);
}

// ---------------- input GEMM + fused colstats ----------------
__global__ __launch_bounds__(256) void in_gemm(const float* __restrict__ x,
                                               const float* __restrict__ W,
                                               const float* __restrict__ b,
                                               float* __restrict__ y,
                                               float* __restrict__ ssum,
                                               float* __restrict__ ssq) {
  __shared__ float xs[32][40];
  __shared__ float s1[256], s2[256];
  int t = threadIdx.x;
  int row0 = blockIdx.x * 32;
  for (int i = t; i < 32 * IN_; i += 256) {
    int r = i / IN_, k = i % IN_;
    int row = row0 + r;
    xs[r][k] = (row < N_) ? x[row * IN_ + k] : 0.f;
  }
  __syncthreads();
  int col = t & 127;
  int half = t >> 7;
  float acc[16];
#pragma unroll
  for (int r = 0; r < 16; r++) acc[r] = 0.f;
  for (int k = 0; k < IN_; k++) {
    float w = W[k * H_ + col];
#pragma unroll
    for (int r = 0; r < 16; r++) acc[r] = fmaf(xs[half * 16 + r][k], w, acc[r]);
  }
  float bb = b[col];
  float a1 = 0.f, a2 = 0.f;
#pragma unroll
  for (int r = 0; r < 16; r++) {
    int row = row0 + half * 16 + r;
    float v = acc[r] + bb;
    if (row < N_) {
      y[row * H_ + col] = v;
      a1 += v;
      a2 = fmaf(v, v, a2);
    }
  }
  s1[t] = a1; s2[t] = a2;
  __syncthreads();
  if (t < 128) {
    atomicAdd(&ssum[t], s1[t] + s1[t + 128]);
    atomicAdd(&ssq[t], s2[t] + s2[t + 128]);
  }
}

// ---------------- MFMA node GEMM (pre-packed bf16 B) ----------
// MODE 1: v=relu(bn(buf)); xn=v.  MODE 2: v=xn+elu(bn(buf)); xn=v.
template <int MODE>
__global__ __launch_bounds__(256) void gemm_mfma(float* __restrict__ xn,
                                                 const float* __restrict__ buf,
                                                 const float* __restrict__ g,
                                                 const float* __restrict__ beta,
                                                 const float* __restrict__ ssum,
                                                 const float* __restrict__ ssq,
                                                 float rows_inv,
                                                 const unsigned short* __restrict__ wp,
                                                 unsigned* __restrict__ xlb,
                                                 unsigned* __restrict__ xrb) {
  __shared__ char smem[17408 + 20480];
  short (*a_s)[136] = (short(*)[136])smem;              // 64 rows x 128 k (pad 136)
  short (*b_s)[40] = (short(*)[40])(smem + 17408);      // 256 n x 32 k (pad 40)
  float* t2base = (float*)(smem + 17408);               // epilogue reuse
  int t = threadIdx.x;
  int lane = t & 63, w = t >> 6;
  int quad = lane >> 4, lc = lane & 15;
  int row0 = blockIdx.x * 64;

  // ---- stage A (fused BN epilogue, fp32 xn updated, bf16 into LDS) ----
  {
    int r = t >> 2;
    int row = row0 + r;
    int kb0 = (t & 3) * 32;
    bool valid = row < N_;
    for (int kk = 0; kk < 32; kk += 4) {
      int c = kb0 + kk;
      float4 v = make_float4(0.f, 0.f, 0.f, 0.f);
      if (valid) {
        float4 bv = *(const float4*)&buf[(size_t)row * H_ + c];
        float4 gv = *(const float4*)&g[c];
        float4 be = *(const float4*)&beta[c];
        float4 s1 = *(const float4*)&ssum[c];
        float4 s2 = *(const float4*)&ssq[c];
        float m0 = s1.x * rows_inv, m1 = s1.y * rows_inv, m2 = s1.z * rows_inv, m3 = s1.w * rows_inv;
        float r0 = rsqrtf(s2.x * rows_inv - m0 * m0 + 1e-5f);
        float r1 = rsqrtf(s2.y * rows_inv - m1 * m1 + 1e-5f);
        float r2 = rsqrtf(s2.z * rows_inv - m2 * m2 + 1e-5f);
        float r3 = rsqrtf(s2.w * rows_inv - m3 * m3 + 1e-5f);
        float t0 = gv.x * (bv.x - m0) * r0 + be.x;
        float t1 = gv.y * (bv.y - m1) * r1 + be.y;
        float t2 = gv.z * (bv.z - m2) * r2 + be.z;
        float t3 = gv.w * (bv.w - m3) * r3 + be.w;
        if (MODE == 1) {
          v = make_float4(fmaxf(t0, 0.f), fmaxf(t1, 0.f), fmaxf(t2, 0.f), fmaxf(t3, 0.f));
        } else {
          float4 xo = *(const float4*)&xn[(size_t)row * H_ + c];
          v.x = xo.x + ((t0 > 0.f) ? t0 : (__expf(t0) - 1.f));
          v.y = xo.y + ((t1 > 0.f) ? t1 : (__expf(t1) - 1.f));
          v.z = xo.z + ((t2 > 0.f) ? t2 : (__expf(t2) - 1.f));
          v.w = xo.w + ((t3 > 0.f) ? t3 : (__expf(t3) - 1.f));
        }
        *(float4*)&xn[(size_t)row * H_ + c] = v;
      }
      uint2 pk;
      pk.x = pk_bf16(v.x, v.y);
      pk.y = pk_bf16(v.z, v.w);
      *(uint2*)&a_s[r][c] = pk;
    }
  }

  f32x4 acc[16];
#pragma unroll
  for (int nt = 0; nt < 16; nt++) acc[nt] = (f32x4){0.f, 0.f, 0.f, 0.f};

  for (int kb = 0; kb < 4; kb++) {
    __syncthreads();
    // stage B chunk: vectorized copy from pre-packed weights (16 KB)
    for (int i = t; i < 1024; i += 256) {
      int n = i >> 2;
      int k8 = (i & 3) * 8;
      *(uint4*)&b_s[n][k8] = *(const uint4*)&wp[(size_t)n * 128 + kb * 32 + k8];
    }
    __syncthreads();
    bf16x8 av = *(const bf16x8*)&a_s[w * 16 + lc][kb * 32 + quad * 8];
#pragma unroll
    for (int nt = 0; nt < 16; nt++) {
      bf16x8 bv = *(const bf16x8*)&b_s[nt * 16 + lc][quad * 8];
      acc[nt] = __builtin_amdgcn_mfma_f32_16x16x32_bf16(av, bv, acc[nt], 0, 0, 0);
    }
  }
  __syncthreads();  // b_s -> t2 reuse

  // ---- epilogue: transpose 16x32 chunks via LDS, packed coalesced stores ----
  float* t2 = t2base + w * 544;  // 16 rows x 34 cols fp32, per-wave private
  for (int ntp = 0; ntp < 8; ntp++) {
#pragma unroll
    for (int rr = 0; rr < 4; rr++) {
      t2[(quad * 4 + rr) * 34 + lc] = acc[2 * ntp][rr];
      t2[(quad * 4 + rr) * 34 + 16 + lc] = acc[2 * ntp + 1][rr];
    }
    __asm__ volatile("s_waitcnt lgkmcnt(0)" ::: "memory");
#pragma unroll
    for (int it = 0; it < 4; it++) {
      int item = lane + it * 64;
      int p = item & 15, rowi = item >> 4;
      float v0 = t2[rowi * 34 + 2 * p];
      float v1 = t2[rowi * 34 + 2 * p + 1];
      unsigned u = pk_bf16(v0, v1);
      int colpair = ntp * 16 + p;
      int rowg = row0 + w * 16 + rowi;
      if (rowg < N_) {
        if (colpair < 64) xlb[(size_t)rowg * 64 + colpair] = u;
        else xrb[(size_t)rowg * 64 + colpair - 64] = u;
      }
    }
    __asm__ volatile("s_waitcnt lgkmcnt(0)" ::: "memory");
  }
}

// ---------------- CSR aggregation (chunk-preload + masked packs) -------------
__device__ __forceinline__ float ep8u(const uint4& u, const float* w) {
  float ep = up_lo(u.x) * w[0];
  ep = fmaf(up_hi(u.x), w[1], ep);
  ep = fmaf(up_lo(u.y), w[2], ep);
  ep = fmaf(up_hi(u.y), w[3], ep);
  ep = fmaf(up_lo(u.z), w[4], ep);
  ep = fmaf(up_hi(u.z), w[5], ep);
  ep = fmaf(up_lo(u.w), w[6], ep);
  ep = fmaf(up_hi(u.w), w[7], ep);
  return ep;
}

// One 4-edge pack. Sources come from the chunk-preloaded lane register `spre`
// via readlane (uniform SGPR) so the xlb gathers and (uniform) eas4 loads all
// issue back-to-back with no esrc-load dependency. MASK=true clamps indices
// (duplicate loads, cheap L1 hits) and zeroes the padded exps.
template <bool MASK>
__device__ __forceinline__ void pack4(int spre, int j, int cnt, int base, int l,
                                      const unsigned* __restrict__ xlb,
                                      const uint4* __restrict__ eas4,
                                      float xr0, float xr1,
                                      const float* w0, const float* w1,
                                      float2 attv,
                                      float& acc0, float& acc1, float& den) {
  int i0 = j;
  int i1 = j + 1, i2 = j + 2, i3 = j + 3;
  if (MASK) {
    i1 = (i1 < cnt) ? i1 : cnt - 1;
    i2 = (i2 < cnt) ? i2 : cnt - 1;
    i3 = (i3 < cnt) ? i3 : cnt - 1;
  }
  int s0 = __builtin_amdgcn_readlane(spre, i0);
  int s1 = __builtin_amdgcn_readlane(spre, i1);
  int s2 = __builtin_amdgcn_readlane(spre, i2);
  int s3 = __builtin_amdgcn_readlane(spre, i3);
  unsigned xu0 = xlb[(size_t)s0 * 64 + l];
  unsigned xu1 = xlb[(size_t)s1 * 64 + l];
  unsigned xu2 = xlb[(size_t)s2 * 64 + l];
  unsigned xu3 = xlb[(size_t)s3 * 64 + l];
  uint4 u0 = eas4[base + i0];
  uint4 u1 = eas4[base + i1];
  uint4 u2 = eas4[base + i2];
  uint4 u3 = eas4[base + i3];
  float x00 = up_lo(xu0), x01 = up_hi(xu0);
  float x10 = up_lo(xu1), x11 = up_hi(xu1);
  float x20 = up_lo(xu2), x21 = up_hi(xu2);
  float x30 = up_lo(xu3), x31 = up_hi(xu3);
  float m00 = x00 + xr0 + ep8u(u0, w0);
  float m01 = x01 + xr1 + ep8u(u0, w1);
  float m10 = x10 + xr0 + ep8u(u1, w0);
  float m11 = x11 + xr1 + ep8u(u1, w1);
  float m20 = x20 + xr0 + ep8u(u2, w0);
  float m21 = x21 + xr1 + ep8u(u2, w1);
  float m30 = x30 + xr0 + ep8u(u3, w0);
  float m31 = x31 + xr1 + ep8u(u3, w1);
  m00 = (m00 > 0.f) ? m00 : 0.2f * m00;
  m01 = (m01 > 0.f) ? m01 : 0.2f * m01;
  m10 = (m10 > 0.f) ? m10 : 0.2f * m10;
  m11 = (m11 > 0.f) ? m11 : 0.2f * m11;
  m20 = (m20 > 0.f) ? m20 : 0.2f * m20;
  m21 = (m21 > 0.f) ? m21 : 0.2f * m21;
  m30 = (m30 > 0.f) ? m30 : 0.2f * m30;
  m31 = (m31 > 0.f) ? m31 : 0.2f * m31;
  float p0 = fmaf(m00, attv.x, m01 * attv.y);
  float p1 = fmaf(m10, attv.x, m11 * attv.y);
  float p2 = fmaf(m20, attv.x, m21 * attv.y);
  float p3 = fmaf(m30, attv.x, m31 * attv.y);
  p0 = row_reduce16(p0);
  p1 = row_reduce16(p1);
  p2 = row_reduce16(p2);
  p3 = row_reduce16(p3);
  float e0v = __expf(p0), e1v = __expf(p1), e2v = __expf(p2), e3v = __expf(p3);
  if (MASK) {
    if (j + 1 >= cnt) e1v = 0.f;
    if (j + 2 >= cnt) e2v = 0.f;
    if (j + 3 >= cnt) e3v = 0.f;
  }
  acc0 = fmaf(e0v, x00, acc0); acc1 = fmaf(e0v, x01, acc1);
  acc0 = fmaf(e1v, x10, acc0); acc1 = fmaf(e1v, x11, acc1);
  acc0 = fmaf(e2v, x20, acc0); acc1 = fmaf(e2v, x21, acc1);
  acc0 = fmaf(e3v, x30, acc0); acc1 = fmaf(e3v, x31, acc1);
  den += (e0v + e1v) + (e2v + e3v);
}

__global__ __launch_bounds__(256) void agg_csr(const int* __restrict__ eoff,
                                               const int* __restrict__ esrc,
                                               const unsigned* __restrict__ easb,
                                               const float* __restrict__ Wel,
                                               const float* __restrict__ attl,
                                               const unsigned* __restrict__ xlb,
                                               const unsigned* __restrict__ xrb,
                                               const float* __restrict__ cb,
                                               float* __restrict__ buf,
                                               float* __restrict__ ssum,
                                               float* __restrict__ ssq) {
  __shared__ float sA[256], sB[256], sC[256], sD[256];
  int t = threadIdx.x;
  int l = t & 63;
  int sub = t >> 6;
  int c0 = l * 2;
  float w0[8], w1[8];
#pragma unroll
  for (int k = 0; k < 8; k++) {
    float2 wv = *(const float2*)&Wel[k * H_ + c0];
    w0[k] = wv.x; w1[k] = wv.y;
  }
  float2 attv = *(const float2*)&attl[c0];
  float2 cbv = *(const float2*)&cb[c0];
  const uint4* eas4 = (const uint4*)easb;
  float a1_0 = 0.f, a1_1 = 0.f, a2_0 = 0.f, a2_1 = 0.f;
  for (int n = blockIdx.x * 4 + sub; n < N_; n += gridDim.x * 4) {
    unsigned xru = xrb[(size_t)n * 64 + l];
    float xr0 = up_lo(xru), xr1 = up_hi(xru);
    int e0 = eoff[n], e1 = eoff[n + 1];
    float acc0 = 0.f, acc1 = 0.f, den = 0.f;
    for (int base = e0; base < e1; base += 64) {
      int cnt = min(64, e1 - base);
      int spre = (base + l < e1) ? esrc[base + l] : 0;
      int j = 0;
      for (; j + 4 <= cnt; j += 4)
        pack4<false>(spre, j, cnt, base, l, xlb, eas4, xr0, xr1, w0, w1, attv,
                     acc0, acc1, den);
      if (j < cnt)
        pack4<true>(spre, j, cnt, base, l, xlb, eas4, xr0, xr1, w0, w1, attv,
                    acc0, acc1, den);
    }
    float inv = 1.f / (den + 1e-16f);
    float h0 = acc0 * inv + cbv.x;
    float h1 = acc1 * inv + cbv.y;
    *(float2*)&buf[(size_t)n * H_ + c0] = make_float2(h0, h1);
    a1_0 += h0; a1_1 += h1;
    a2_0 = fmaf(h0, h0, a2_0); a2_1 = fmaf(h1, h1, a2_1);
  }
  sA[t] = a1_0; sB[t] = a1_1; sC[t] = a2_0; sD[t] = a2_1;
  __syncthreads();
  if (t < 64) {
    float r1 = sA[t] + sA[t + 64] + sA[t + 128] + sA[t + 192];
    float r2 = sB[t] + sB[t + 64] + sB[t + 128] + sB[t + 192];
    float r3 = sC[t] + sC[t + 64] + sC[t + 128] + sC[t + 192];
    float r4 = sD[t] + sD[t + 64] + sD[t + 128] + sD[t + 192];
    atomicAdd(&ssum[2 * t], r1);
    atomicAdd(&ssum[2 * t + 1], r2);
    atomicAdd(&ssq[2 * t], r3);
    atomicAdd(&ssq[2 * t + 1], r4);
  }
}

// ---------------- BN apply with inline finalize ----------------
__global__ __launch_bounds__(256) void apply_bn_relu(const float* __restrict__ y,
                                                     float* __restrict__ out,
                                                     const float* __restrict__ g,
                                                     const float* __restrict__ beta,
                                                     const float* __restrict__ ssum,
                                                     const float* __restrict__ ssq,
                                                     float rows_inv,
                                                     long total, int cmask) {
  long i = (long)blockIdx.x * 256 + threadIdx.x;
  if (i >= total) return;
  int c = (int)i & cmask;
  float m = ssum[c] * rows_inv;
  float rs = rsqrtf(ssq[c] * rows_inv - m * m + 1e-5f);
  float v = g[c] * (y[i] - m) * rs + beta[c];
  out[i] = fmaxf(v, 0.f);
}

// ---------------- pooling with fused layer-2 residual (inline BN finalize) ----
__global__ __launch_bounds__(128) void pool_residual(const int* __restrict__ goff,
                                                     const float* __restrict__ xn,
                                                     const float* __restrict__ buf,
                                                     const float* __restrict__ g,
                                                     const float* __restrict__ beta,
                                                     const float* __restrict__ ssum,
                                                     const float* __restrict__ ssq,
                                                     float rows_inv,
                                                     float* __restrict__ xg) {
  int gr = blockIdx.x;
  int t = threadIdx.x;
  int n0 = goff[gr], n1 = goff[gr + 1];
  float mm = ssum[t] * rows_inv;
  float rr = rsqrtf(ssq[t] * rows_inv - mm * mm + 1e-5f);
  float gg = g[t], bb = beta[t];
  float s = 0.f, mx = -INFINITY;
  for (int n = n0; n < n1; n++) {
    float w = gg * (buf[(size_t)n * H_ + t] - mm) * rr + bb;
    w = (w > 0.f) ? w : (__expf(w) - 1.f);
    float v = xn[(size_t)n * H_ + t] + w;
    s += v;
    mx = fmaxf(mx, v);
  }
  float c = (float)(n1 - n0);
  xg[gr * 384 + t] = s / fmaxf(c, 1.f);
  xg[gr * 384 + 128 + t] = (c > 0.f) ? mx : 0.f;
  xg[gr * 384 + 256 + t] = s;
}

// ---------------- MLP GEMMs (fused colstats) ----------------
template <int K, int COLS>
__global__ void mlp_gemm(const float* __restrict__ A, const float* __restrict__ W,
                         const float* __restrict__ b, float* __restrict__ Y, int rows,
                         float* __restrict__ ssum, float* __restrict__ ssq) {
  __shared__ float xs[8][K];
  int t = threadIdx.x;
  int row0 = blockIdx.x * 8;
  for (int i = t; i < 8 * K; i += COLS) {
    int r = i / K, k = i % K;
    int row = row0 + r;
    xs[r][k] = (row < rows) ? A[row * K + k] : 0.f;
  }
  __syncthreads();
  float acc[8];
#pragma unroll
  for (int r = 0; r < 8; r++) acc[r] = 0.f;
  for (int k = 0; k < K; k++) {
    float w = W[k * COLS + t];
#pragma unroll
    for (int r = 0; r < 8; r++) acc[r] = fmaf(xs[r][k], w, acc[r]);
  }
  float bb = b[t];
  float a1 = 0.f, a2 = 0.f;
#pragma unroll
  for (int r = 0; r < 8; r++) {
    int row = row0 + r;
    if (row < rows) {
      float v = acc[r] + bb;
      Y[row * COLS + t] = v;
      a1 += v;
      a2 = fmaf(v, v, a2);
    }
  }
  atomicAdd(&ssum[t], a1);
  atomicAdd(&ssq[t], a2);
}

// ---------------- head ----------------
__global__ __launch_bounds__(64) void head_kernel(const float* __restrict__ u,
                                                  const float* __restrict__ W,
                                                  const float* __restrict__ b,
                                                  float* __restrict__ out) {
  __shared__ float row[128];
  int g = blockIdx.x;
  int t = threadIdx.x;
  row[t] = u[g * 128 + t];
  row[t + 64] = u[g * 128 + 64 + t];
  __syncthreads();
  if (t < 12) {
    float acc = b[t];
    for (int k = 0; k < 128; k++) acc = fmaf(row[k], W[k * 12 + t], acc);
    out[g * 12 + t] = 1.f / (1.f + expf(-acc));
  }
}

// ---------------- launcher ----------------
extern "C" void kernel_launch(void* const* d_in, const int* in_sizes, int n_in, void* d_out,
                              int out_size, void* d_ws, size_t ws_size, hipStream_t stream) {
  (void)in_sizes; (void)n_in; (void)out_size; (void)ws_size;
  const float* x       = (const float*)d_in[0];
  const int*   ei      = (const int*)d_in[1];
  const float* ea      = (const float*)d_in[2];
  const int*   batch   = (const int*)d_in[3];
  const float* in_W    = (const float*)d_in[4];
  const float* in_b    = (const float*)d_in[5];
  const float* in_g    = (const float*)d_in[6];
  const float* in_beta = (const float*)d_in[7];
  const float* Wl      = (const float*)d_in[8];
  const float* Wr      = (const float*)d_in[9];
  const float* We      = (const float*)d_in[10];
  const float* att     = (const float*)d_in[11];
  const float* conv_b  = (const float*)d_in[12];
  const float* bn_g    = (const float*)d_in[13];
  const float* bn_b    = (const float*)d_in[14];
  const float* t1_W    = (const float*)d_in[15];
  const float* t1_b    = (const float*)d_in[16];
  const float* t1_g    = (const float*)d_in[17];
  const float* t1_beta = (const float*)d_in[18];
  const float* t2_W    = (const float*)d_in[19];
  const float* t2_b    = (const float*)d_in[20];
  const float* t2_g    = (const float*)d_in[21];
  const float* t2_beta = (const float*)d_in[22];
  const float* head_W  = (const float*)d_in[23];
  const float* head_b  = (const float*)d_in[24];
  float* out = (float*)d_out;

  float* p = (float*)d_ws;
  float* xn    = p; p += N_ * H_;
  float* buf   = p; p += N_ * H_;
  float* sstat = p; p += 6 * 512;   // 6 stages x (ssum 256 | ssq 256)
  float* xg    = p; p += G_ * 384;
  float* u1    = p; p += G_ * 256;
  float* u2    = p; p += G_ * 128;
  unsigned* up = (unsigned*)p;
  unsigned* xlb  = up; up += (size_t)N_ * 64;
  unsigned* xrb  = up; up += (size_t)N_ * 64;
  unsigned* easb = up; up += (size_t)E_ * 4;
  unsigned short* wpack = (unsigned short*)up; up += 3 * 32768 / 2;
  int* ip = (int*)up;
  int* deg    = ip; ip += N_;
  int* eoff   = ip; ip += N_ + 1;
  int* cursor = ip; ip += N_;
  int* goff   = ip; ip += G_ + 1;
  int* esrc   = ip; ip += E_;
  int* bsum   = ip; ip += 64;
  int* boff   = ip; ip += 64;

#define SSUM(s) (sstat + (s) * 512)
#define SSQ(s)  (sstat + (s) * 512 + 256)

  // ---- build CSR structures + pre-pack weights ----
  hipMemsetAsync(deg, 0, (size_t)N_ * sizeof(int), stream);
  hipMemsetAsync(sstat, 0, 6 * 512 * sizeof(float), stream);
  hist_kernel<<<1024, 256, 0, stream>>>(ei + E_, E_, deg);
  scan_local<<<49, 1024, 0, stream>>>(deg, eoff, bsum, N_);
  scan_bsum<<<1, 64, 0, stream>>>(bsum, boff, 49);
  scan_add<<<49, 1024, 0, stream>>>(eoff, boff, cursor, N_);
  edge_scatter<<<(E_ + 255) / 256, 256, 0, stream>>>(ei, ea, cursor, esrc, easb);
  goff_from_sorted<<<(N_ + 255) / 256, 256, 0, stream>>>(batch, goff);
  pack_weights<<<384, 256, 0, stream>>>(Wl, Wr, wpack);

  // ---- input layer (stats -> stage 0) ----
  in_gemm<<<(N_ + 31) / 32, 256, 0, stream>>>(x, in_W, in_b, buf, SSUM(0), SSQ(0));

  // ---- 3 GATv2 layers (conv stats of layer l -> stage l+1) ----
  const float rnInv = 1.f / N_;
  for (int l = 0; l < 3; l++) {
    if (l == 0) {
      gemm_mfma<1><<<782, 256, 0, stream>>>(xn, buf, in_g, in_beta, SSUM(0), SSQ(0), rnInv,
                                            wpack + (size_t)l * 32768, xlb, xrb);
    } else {
      gemm_mfma<2><<<782, 256, 0, stream>>>(xn, buf, bn_g + (l - 1) * H_, bn_b + (l - 1) * H_,
                                            SSUM(l), SSQ(l), rnInv,
                                            wpack + (size_t)l * 32768, xlb, xrb);
    }
    agg_csr<<<2048, 256, 0, stream>>>(eoff, esrc, easb, We + l * 8 * H_, att + l * H_,
                                      xlb, xrb, conv_b + l * H_, buf, SSUM(l + 1), SSQ(l + 1));
  }

  // ---- pooling with fused layer-2 residual (stage 3 stats) ----
  pool_residual<<<G_, 128, 0, stream>>>(goff, xn, buf, bn_g + 2 * H_, bn_b + 2 * H_,
                                        SSUM(3), SSQ(3), rnInv, xg);

  // ---- t1 (stats -> stage 4) ----
  const float rgInv = 1.f / G_;
  mlp_gemm<384, 256><<<G_ / 8, 256, 0, stream>>>(xg, t1_W, t1_b, u1, G_, SSUM(4), SSQ(4));
  apply_bn_relu<<<(G_ * 256 + 255) / 256, 256, 0, stream>>>(u1, u1, t1_g, t1_beta,
                                                            SSUM(4), SSQ(4), rgInv,
                                                            (long)G_ * 256, 255);

  // ---- t2 (stats -> stage 5) ----
  mlp_gemm<256, 128><<<G_ / 8, 128, 0, stream>>>(u1, t2_W, t2_b, u2, G_, SSUM(5), SSQ(5));
  apply_bn_relu<<<(G_ * 128 + 255) / 256, 256, 0, stream>>>(u2, u2, t2_g, t2_beta,
                                                            SSUM(5), SSQ(5), rgInv,
                                                            (long)G_ * 128, 127);

  // ---- head ----
  head_kernel<<<G_, 64, 0, stream>>>(u2, head_W, head_b, out);
#undef SSUM
#undef SSQ
}

// Round 5
// 841.389 us; speedup vs baseline: 1.0359x; 1.0128x over previous
//
#include <hip/hip_runtime.h>
#include <math.h>

// ToxicityGATv2 — round 14: resubmit of round 13 (infra failure, no data) with
// one hardening change: explicit lgkmcnt(0) after the LDS attr-staging write.
//  * node PAIRING: wave handles nodes (2p,2p+1); adjacent CSR ranges share ONE
//    esrc chunk preload + ONE coalesced attr window (guard: pair deg <= 64,
//    else r12 solo fallback)
//  * pair attrs staged to a per-wave LDS slice; compute reads them as uniform
//    broadcast loads (no VGPR state, no attr latency on the pack critical path)
//  * rolling 1-deep gather prefetch: pack k+1's xlb gathers (4 VGPR) issue
//    before pack k's compute
// DPP reduce kept from r11. Target: VGPR <= 64 (8 waves/SIMD preserved).

constexpr int N_ = 50000;
constexpr int E_ = 400000;
constexpr int G_ = 2000;
constexpr int H_ = 128;
constexpr int IN_ = 39;

typedef __attribute__((ext_vector_type(8))) short bf16x8;
typedef __attribute__((ext_vector_type(4))) float f32x4;

// ---------------- bf16 pack/unpack (RNE) ----------------
__device__ __forceinline__ unsigned pk_bf16(float a, float b) {
  unsigned ua = __float_as_uint(a);
  unsigned ub = __float_as_uint(b);
  ua = (ua + 0x7fffu + ((ua >> 16) & 1u)) >> 16;
  ub = (ub + 0x7fffu + ((ub >> 16) & 1u)) & 0xffff0000u;
  return ua | ub;
}
__device__ __forceinline__ unsigned short bf16_1(float x) {
  unsigned u = __float_as_uint(x);
  u = (u + 0x7fffu + ((u >> 16) & 1u)) >> 16;
  return (unsigned short)u;
}
__device__ __forceinline__ float up_lo(unsigned u) { return __uint_as_float(u << 16); }
__device__ __forceinline__ float up_hi(unsigned u) { return __uint_as_float(u & 0xffff0000u); }

// ---------------- DPP rotate-reduce over 16-lane rows (VALU pipe, no LDS) ----
template <int CTRL>
__device__ __forceinline__ float dpp_radd(float x) {
  int y = __builtin_amdgcn_update_dpp(0, __float_as_int(x), CTRL, 0xF, 0xF, false);
  return x + __int_as_float(y);
}
__device__ __forceinline__ float row_reduce16(float p) {
  p = dpp_radd<0x121>(p);  // row_ror:1
  p = dpp_radd<0x122>(p);  // row_ror:2
  p = dpp_radd<0x124>(p);  // row_ror:4
  p = dpp_radd<0x128>(p);  // row_ror:8
  return p;
}

// ---------------- histogram ----------------
__global__ __launch_bounds__(256) void hist_kernel(const int* __restrict__ keys, int n,
                                                   int* __restrict__ cnt) {
  for (int i = blockIdx.x * 256 + threadIdx.x; i < n; i += gridDim.x * 256)
    atomicAdd(&cnt[keys[i]], 1);
}

// ---------------- multi-block scan ----------------
__global__ __launch_bounds__(1024) void scan_local(const int* __restrict__ in,
                                                   int* __restrict__ outx,
                                                   int* __restrict__ bsum, int n) {
  __shared__ int wsum[16];
  int t = threadIdx.x, lane = t & 63, wid = t >> 6;
  int idx = blockIdx.x * 1024 + t;
  int v = (idx < n) ? in[idx] : 0;
  int x = v;
#pragma unroll
  for (int off = 1; off < 64; off <<= 1) {
    int y = __shfl_up(x, off, 64);
    if (lane >= off) x += y;
  }
  if (lane == 63) wsum[wid] = x;
  __syncthreads();
  if (t == 0) {
    int acc = 0;
#pragma unroll
    for (int w = 0; w < 16; w++) { int tmp = wsum[w]; wsum[w] = acc; acc += tmp; }
    bsum[blockIdx.x] = acc;
  }
  __syncthreads();
  if (idx < n) outx[idx] = wsum[wid] + x - v;
}

__global__ __launch_bounds__(64) void scan_bsum(const int* __restrict__ bsum,
                                                int* __restrict__ boff, int nb) {
  int t = threadIdx.x;
  int v = (t < nb) ? bsum[t] : 0;
  int x = v;
#pragma unroll
  for (int off = 1; off < 64; off <<= 1) {
    int y = __shfl_up(x, off, 64);
    if (t >= off) x += y;
  }
  boff[t] = x - v;
}

__global__ __launch_bounds__(1024) void scan_add(int* __restrict__ eoff,
                                                 const int* __restrict__ boff,
                                                 int* __restrict__ cursor, int n) {
  int idx = blockIdx.x * 1024 + threadIdx.x;
  if (idx < n) {
    int e = eoff[idx] + boff[idx >> 10];
    eoff[idx] = e;
    cursor[idx] = e;
  }
  if (idx == 0) eoff[n] = E_;
}

// ---------------- goff from sorted batch ----------------
__global__ __launch_bounds__(256) void goff_from_sorted(const int* __restrict__ batch,
                                                        int* __restrict__ goff) {
  int i = blockIdx.x * 256 + threadIdx.x;
  if (i >= N_) return;
  int bi = batch[i];
  int bp = (i == 0) ? -1 : batch[i - 1];
  for (int g = bp + 1; g <= bi; g++) goff[g] = i;
  if (i == N_ - 1) {
    for (int g = bi + 1; g <= G_; g++) goff[g] = N_;
  }
}

// ---------------- edge scatter (bf16 attrs) ----------------
__global__ __launch_bounds__(256) void edge_scatter(const int* __restrict__ ei,
                                                    const float* __restrict__ ea,
                                                    int* __restrict__ cursor,
                                                    int* __restrict__ esrc,
                                                    unsigned* __restrict__ easb) {
  int e = blockIdx.x * 256 + threadIdx.x;
  if (e >= E_) return;
  int src = ei[e];
  int dst = ei[E_ + e];
  int j = atomicAdd(&cursor[dst], 1);
  esrc[j] = src;
  const float4* eav = (const float4*)(ea + (size_t)e * 8);
  float4 a0 = eav[0], a1 = eav[1];
  uint4 o;
  o.x = pk_bf16(a0.x, a0.y);
  o.y = pk_bf16(a0.z, a0.w);
  o.z = pk_bf16(a1.x, a1.y);
  o.w = pk_bf16(a1.z, a1.w);
  ((uint4*)easb)[j] = o;
}

// ---------------- weight pre-pack: wpack[l][n][k] = bf16([Wl|Wr][k][n]) -------
__global__ __launch_bounds__(256) void pack_weights(const float* __restrict__ Wl,
                                                    const float* __restrict__ Wr,
                                                    unsigned short* __restrict__ wpack) {
  int i = blockIdx.x * 256 + threadIdx.x;  // enumerate (l, k, n) read-coalesced
  if (i >= 3 * 128 * 256) return;
  int l = i >> 15;
  int rem = i & 32767;
  int k = rem >> 8;
  int n = rem & 255;
  const float* Wsrc = (n < 128) ? (Wl + l * H_ * H_) : (Wr + l * H_ * H_);
  int nn = n & 127;
  wpack[(size_t)l * 32768 + n * 128 + k] = bf16_1(Wsrc[k * H_ + nn]);
}

// ---------------- input GEMM + fused colstats ----------------
__global__ __launch_bounds__(256) void in_gemm(const float* __restrict__ x,
                                               const float* __restrict__ W,
                                               const float* __restrict__ b,
                                               float* __restrict__ y,
                                               float* __restrict__ ssum,
                                               float* __restrict__ ssq) {
  __shared__ float xs[32][40];
  __shared__ float s1[256], s2[256];
  int t = threadIdx.x;
  int row0 = blockIdx.x * 32;
  for (int i = t; i < 32 * IN_; i += 256) {
    int r = i / IN_, k = i % IN_;
    int row = row0 + r;
    xs[r][k] = (row < N_) ? x[row * IN_ + k] : 0.f;
  }
  __syncthreads();
  int col = t & 127;
  int half = t >> 7;
  float acc[16];
#pragma unroll
  for (int r = 0; r < 16; r++) acc[r] = 0.f;
  for (int k = 0; k < IN_; k++) {
    float w = W[k * H_ + col];
#pragma unroll
    for (int r = 0; r < 16; r++) acc[r] = fmaf(xs[half * 16 + r][k], w, acc[r]);
  }
  float bb = b[col];
  float a1 = 0.f, a2 = 0.f;
#pragma unroll
  for (int r = 0; r < 16; r++) {
    int row = row0 + half * 16 + r;
    float v = acc[r] + bb;
    if (row < N_) {
      y[row * H_ + col] = v;
      a1 += v;
      a2 = fmaf(v, v, a2);
    }
  }
  s1[t] = a1; s2[t] = a2;
  __syncthreads();
  if (t < 128) {
    atomicAdd(&ssum[t], s1[t] + s1[t + 128]);
    atomicAdd(&ssq[t], s2[t] + s2[t + 128]);
  }
}

// ---------------- MFMA node GEMM (pre-packed bf16 B) ----------
// MODE 1: v=relu(bn(buf)); xn=v.  MODE 2: v=xn+elu(bn(buf)); xn=v.
template <int MODE>
__global__ __launch_bounds__(256) void gemm_mfma(float* __restrict__ xn,
                                                 const float* __restrict__ buf,
                                                 const float* __restrict__ g,
                                                 const float* __restrict__ beta,
                                                 const float* __restrict__ ssum,
                                                 const float* __restrict__ ssq,
                                                 float rows_inv,
                                                 const unsigned short* __restrict__ wp,
                                                 unsigned* __restrict__ xlb,
                                                 unsigned* __restrict__ xrb) {
  __shared__ char smem[17408 + 20480];
  short (*a_s)[136] = (short(*)[136])smem;              // 64 rows x 128 k (pad 136)
  short (*b_s)[40] = (short(*)[40])(smem + 17408);      // 256 n x 32 k (pad 40)
  float* t2base = (float*)(smem + 17408);               // epilogue reuse
  int t = threadIdx.x;
  int lane = t & 63, w = t >> 6;
  int quad = lane >> 4, lc = lane & 15;
  int row0 = blockIdx.x * 64;

  // ---- stage A (fused BN epilogue, fp32 xn updated, bf16 into LDS) ----
  {
    int r = t >> 2;
    int row = row0 + r;
    int kb0 = (t & 3) * 32;
    bool valid = row < N_;
    for (int kk = 0; kk < 32; kk += 4) {
      int c = kb0 + kk;
      float4 v = make_float4(0.f, 0.f, 0.f, 0.f);
      if (valid) {
        float4 bv = *(const float4*)&buf[(size_t)row * H_ + c];
        float4 gv = *(const float4*)&g[c];
        float4 be = *(const float4*)&beta[c];
        float4 s1 = *(const float4*)&ssum[c];
        float4 s2 = *(const float4*)&ssq[c];
        float m0 = s1.x * rows_inv, m1 = s1.y * rows_inv, m2 = s1.z * rows_inv, m3 = s1.w * rows_inv;
        float r0 = rsqrtf(s2.x * rows_inv - m0 * m0 + 1e-5f);
        float r1 = rsqrtf(s2.y * rows_inv - m1 * m1 + 1e-5f);
        float r2 = rsqrtf(s2.z * rows_inv - m2 * m2 + 1e-5f);
        float r3 = rsqrtf(s2.w * rows_inv - m3 * m3 + 1e-5f);
        float t0 = gv.x * (bv.x - m0) * r0 + be.x;
        float t1 = gv.y * (bv.y - m1) * r1 + be.y;
        float t2 = gv.z * (bv.z - m2) * r2 + be.z;
        float t3 = gv.w * (bv.w - m3) * r3 + be.w;
        if (MODE == 1) {
          v = make_float4(fmaxf(t0, 0.f), fmaxf(t1, 0.f), fmaxf(t2, 0.f), fmaxf(t3, 0.f));
        } else {
          float4 xo = *(const float4*)&xn[(size_t)row * H_ + c];
          v.x = xo.x + ((t0 > 0.f) ? t0 : (__expf(t0) - 1.f));
          v.y = xo.y + ((t1 > 0.f) ? t1 : (__expf(t1) - 1.f));
          v.z = xo.z + ((t2 > 0.f) ? t2 : (__expf(t2) - 1.f));
          v.w = xo.w + ((t3 > 0.f) ? t3 : (__expf(t3) - 1.f));
        }
        *(float4*)&xn[(size_t)row * H_ + c] = v;
      }
      uint2 pk;
      pk.x = pk_bf16(v.x, v.y);
      pk.y = pk_bf16(v.z, v.w);
      *(uint2*)&a_s[r][c] = pk;
    }
  }

  f32x4 acc[16];
#pragma unroll
  for (int nt = 0; nt < 16; nt++) acc[nt] = (f32x4){0.f, 0.f, 0.f, 0.f};

  for (int kb = 0; kb < 4; kb++) {
    __syncthreads();
    // stage B chunk: vectorized copy from pre-packed weights (16 KB)
    for (int i = t; i < 1024; i += 256) {
      int n = i >> 2;
      int k8 = (i & 3) * 8;
      *(uint4*)&b_s[n][k8] = *(const uint4*)&wp[(size_t)n * 128 + kb * 32 + k8];
    }
    __syncthreads();
    bf16x8 av = *(const bf16x8*)&a_s[w * 16 + lc][kb * 32 + quad * 8];
#pragma unroll
    for (int nt = 0; nt < 16; nt++) {
      bf16x8 bv = *(const bf16x8*)&b_s[nt * 16 + lc][quad * 8];
      acc[nt] = __builtin_amdgcn_mfma_f32_16x16x32_bf16(av, bv, acc[nt], 0, 0, 0);
    }
  }
  __syncthreads();  // b_s -> t2 reuse

  // ---- epilogue: transpose 16x32 chunks via LDS, packed coalesced stores ----
  float* t2 = t2base + w * 544;  // 16 rows x 34 cols fp32, per-wave private
  for (int ntp = 0; ntp < 8; ntp++) {
#pragma unroll
    for (int rr = 0; rr < 4; rr++) {
      t2[(quad * 4 + rr) * 34 + lc] = acc[2 * ntp][rr];
      t2[(quad * 4 + rr) * 34 + 16 + lc] = acc[2 * ntp + 1][rr];
    }
    __asm__ volatile("s_waitcnt lgkmcnt(0)" ::: "memory");
#pragma unroll
    for (int it = 0; it < 4; it++) {
      int item = lane + it * 64;
      int p = item & 15, rowi = item >> 4;
      float v0 = t2[rowi * 34 + 2 * p];
      float v1 = t2[rowi * 34 + 2 * p + 1];
      unsigned u = pk_bf16(v0, v1);
      int colpair = ntp * 16 + p;
      int rowg = row0 + w * 16 + rowi;
      if (rowg < N_) {
        if (colpair < 64) xlb[(size_t)rowg * 64 + colpair] = u;
        else xrb[(size_t)rowg * 64 + colpair - 64] = u;
      }
    }
    __asm__ volatile("s_waitcnt lgkmcnt(0)" ::: "memory");
  }
}

// ---------------- CSR aggregation (paired nodes + rolling prefetch) ----------
__device__ __forceinline__ float ep8u(const uint4& u, const float* w) {
  float ep = up_lo(u.x) * w[0];
  ep = fmaf(up_hi(u.x), w[1], ep);
  ep = fmaf(up_lo(u.y), w[2], ep);
  ep = fmaf(up_hi(u.y), w[3], ep);
  ep = fmaf(up_lo(u.z), w[4], ep);
  ep = fmaf(up_hi(u.z), w[5], ep);
  ep = fmaf(up_lo(u.w), w[6], ep);
  ep = fmaf(up_hi(u.w), w[7], ep);
  return ep;
}

// r12 solo pack (global attr loads) — used only on the rare fallback path.
template <bool MASK>
__device__ __forceinline__ void pack4(int spre, int j, int cnt, int base, int l,
                                      const unsigned* __restrict__ xlb,
                                      const uint4* __restrict__ eas4,
                                      float xr0, float xr1,
                                      const float* w0, const float* w1,
                                      float2 attv,
                                      float& acc0, float& acc1, float& den) {
  int i0 = j;
  int i1 = j + 1, i2 = j + 2, i3 = j + 3;
  if (MASK) {
    i1 = (i1 < cnt) ? i1 : cnt - 1;
    i2 = (i2 < cnt) ? i2 : cnt - 1;
    i3 = (i3 < cnt) ? i3 : cnt - 1;
  }
  int s0 = __builtin_amdgcn_readlane(spre, i0);
  int s1 = __builtin_amdgcn_readlane(spre, i1);
  int s2 = __builtin_amdgcn_readlane(spre, i2);
  int s3 = __builtin_amdgcn_readlane(spre, i3);
  unsigned xu0 = xlb[(size_t)s0 * 64 + l];
  unsigned xu1 = xlb[(size_t)s1 * 64 + l];
  unsigned xu2 = xlb[(size_t)s2 * 64 + l];
  unsigned xu3 = xlb[(size_t)s3 * 64 + l];
  uint4 u0 = eas4[base + i0];
  uint4 u1 = eas4[base + i1];
  uint4 u2 = eas4[base + i2];
  uint4 u3 = eas4[base + i3];
  float x00 = up_lo(xu0), x01 = up_hi(xu0);
  float x10 = up_lo(xu1), x11 = up_hi(xu1);
  float x20 = up_lo(xu2), x21 = up_hi(xu2);
  float x30 = up_lo(xu3), x31 = up_hi(xu3);
  float m00 = x00 + xr0 + ep8u(u0, w0);
  float m01 = x01 + xr1 + ep8u(u0, w1);
  float m10 = x10 + xr0 + ep8u(u1, w0);
  float m11 = x11 + xr1 + ep8u(u1, w1);
  float m20 = x20 + xr0 + ep8u(u2, w0);
  float m21 = x21 + xr1 + ep8u(u2, w1);
  float m30 = x30 + xr0 + ep8u(u3, w0);
  float m31 = x31 + xr1 + ep8u(u3, w1);
  m00 = (m00 > 0.f) ? m00 : 0.2f * m00;
  m01 = (m01 > 0.f) ? m01 : 0.2f * m01;
  m10 = (m10 > 0.f) ? m10 : 0.2f * m10;
  m11 = (m11 > 0.f) ? m11 : 0.2f * m11;
  m20 = (m20 > 0.f) ? m20 : 0.2f * m20;
  m21 = (m21 > 0.f) ? m21 : 0.2f * m21;
  m30 = (m30 > 0.f) ? m30 : 0.2f * m30;
  m31 = (m31 > 0.f) ? m31 : 0.2f * m31;
  float p0 = fmaf(m00, attv.x, m01 * attv.y);
  float p1 = fmaf(m10, attv.x, m11 * attv.y);
  float p2 = fmaf(m20, attv.x, m21 * attv.y);
  float p3 = fmaf(m30, attv.x, m31 * attv.y);
  p0 = row_reduce16(p0);
  p1 = row_reduce16(p1);
  p2 = row_reduce16(p2);
  p3 = row_reduce16(p3);
  float e0v = __expf(p0), e1v = __expf(p1), e2v = __expf(p2), e3v = __expf(p3);
  if (MASK) {
    if (j + 1 >= cnt) e1v = 0.f;
    if (j + 2 >= cnt) e2v = 0.f;
    if (j + 3 >= cnt) e3v = 0.f;
  }
  acc0 = fmaf(e0v, x00, acc0); acc1 = fmaf(e0v, x01, acc1);
  acc0 = fmaf(e1v, x10, acc0); acc1 = fmaf(e1v, x11, acc1);
  acc0 = fmaf(e2v, x20, acc0); acc1 = fmaf(e2v, x21, acc1);
  acc0 = fmaf(e3v, x30, acc0); acc1 = fmaf(e3v, x31, acc1);
  den += (e0v + e1v) + (e2v + e3v);
}

__device__ __forceinline__ void solo_node(int e0, int e1, int l,
                                          const int* __restrict__ esrc,
                                          const unsigned* __restrict__ xlb,
                                          const uint4* __restrict__ eas4,
                                          float xr0, float xr1,
                                          const float* w0, const float* w1,
                                          float2 attv,
                                          float& acc0, float& acc1, float& den) {
  for (int base = e0; base < e1; base += 64) {
    int cnt = min(64, e1 - base);
    int spre = (base + l < e1) ? esrc[base + l] : 0;
    int j = 0;
    for (; j + 4 <= cnt; j += 4)
      pack4<false>(spre, j, cnt, base, l, xlb, eas4, xr0, xr1, w0, w1, attv, acc0, acc1, den);
    if (j < cnt)
      pack4<true>(spre, j, cnt, base, l, xlb, eas4, xr0, xr1, w0, w1, attv, acc0, acc1, den);
  }
}

__global__ __launch_bounds__(256) void agg_csr(const int* __restrict__ eoff,
                                               const int* __restrict__ esrc,
                                               const unsigned* __restrict__ easb,
                                               const float* __restrict__ Wel,
                                               const float* __restrict__ attl,
                                               const unsigned* __restrict__ xlb,
                                               const unsigned* __restrict__ xrb,
                                               const float* __restrict__ cb,
                                               float* __restrict__ buf,
                                               float* __restrict__ ssum,
                                               float* __restrict__ ssq) {
  __shared__ float sA[256], sB[256], sC[256], sD[256];
  __shared__ uint4 eaLds[4][64];   // per-wave attr window (1 KB each)
  int t = threadIdx.x;
  int l = t & 63;
  int sub = t >> 6;
  int c0 = l * 2;
  uint4* eaW = &eaLds[sub][0];
  float w0[8], w1[8];
#pragma unroll
  for (int k = 0; k < 8; k++) {
    float2 wv = *(const float2*)&Wel[k * H_ + c0];
    w0[k] = wv.x; w1[k] = wv.y;
  }
  float2 attv = *(const float2*)&attl[c0];
  float2 cbv = *(const float2*)&cb[c0];
  const uint4* eas4 = (const uint4*)easb;
  float a1_0 = 0.f, a1_1 = 0.f, a2_0 = 0.f, a2_1 = 0.f;

  for (int pi = blockIdx.x * 4 + sub; pi < N_ / 2; pi += gridDim.x * 4) {
    int nA = 2 * pi, nB = nA + 1;
    int e0A = eoff[nA], e1A = eoff[nA + 1], e1B = eoff[nA + 2];
    unsigned xruA = xrb[(size_t)nA * 64 + l];
    unsigned xruB = xrb[(size_t)nB * 64 + l];
    int cE = e1B - e0A;
    float hA0, hA1, hB0, hB1;
    if (cE <= 64) {
      int cA = e1A - e0A, cB = e1B - e1A;
      // stage pair attrs to LDS (one coalesced load) + esrc chunk to lane reg
      if (l < cE) eaW[l] = eas4[e0A + l];
      int spre = (l < cE) ? esrc[e0A + l] : 0;
      __asm__ volatile("s_waitcnt lgkmcnt(0)" ::: "memory");
      int nPA = (cA + 3) >> 2;
      int nP = nPA + ((cB + 3) >> 2);
      float accA0 = 0.f, accA1 = 0.f, denA = 0.f;
      float accB0 = 0.f, accB1 = 0.f, denB = 0.f;
      unsigned xu0 = 0, xu1 = 0, xu2 = 0, xu3 = 0;
      int i0 = 0, i1 = 0, i2 = 0, i3 = 0;  // uniform pack indices (local)
      if (nP > 0) {  // prefetch pack 0
        bool isA = 0 < nPA;
        int off = isA ? 0 : cA;
        int cnt = isA ? cA : cB;
        int lim = off + cnt - 1;
        i0 = off;
        i1 = min(off + 1, lim); i2 = min(off + 2, lim); i3 = min(off + 3, lim);
        xu0 = xlb[(size_t)__builtin_amdgcn_readlane(spre, i0) * 64 + l];
        xu1 = xlb[(size_t)__builtin_amdgcn_readlane(spre, i1) * 64 + l];
        xu2 = xlb[(size_t)__builtin_amdgcn_readlane(spre, i2) * 64 + l];
        xu3 = xlb[(size_t)__builtin_amdgcn_readlane(spre, i3) * 64 + l];
      }
      for (int k = 0; k < nP; k++) {
        unsigned t0 = xu0, t1 = xu1, t2 = xu2, t3 = xu3;
        int ci0 = i0, ci1 = i1, ci2 = i2, ci3 = i3;
        bool isA = k < nPA;
        int j = isA ? 4 * k : 4 * (k - nPA);
        int cnt = isA ? cA : cB;
        if (k + 1 < nP) {  // prefetch pack k+1 (gathers only, 4 VGPR)
          bool pA = (k + 1) < nPA;
          int off2 = pA ? 0 : cA;
          int cnt2 = pA ? cA : cB;
          int j2 = pA ? 4 * (k + 1) : 4 * (k + 1 - nPA);
          int b2 = off2 + j2;
          int lim2 = off2 + cnt2 - 1;
          i0 = b2;
          i1 = min(b2 + 1, lim2); i2 = min(b2 + 2, lim2); i3 = min(b2 + 3, lim2);
          xu0 = xlb[(size_t)__builtin_amdgcn_readlane(spre, i0) * 64 + l];
          xu1 = xlb[(size_t)__builtin_amdgcn_readlane(spre, i1) * 64 + l];
          xu2 = xlb[(size_t)__builtin_amdgcn_readlane(spre, i2) * 64 + l];
          xu3 = xlb[(size_t)__builtin_amdgcn_readlane(spre, i3) * 64 + l];
        }
        // attrs from LDS (uniform broadcast reads)
        uint4 u0 = eaW[ci0], u1 = eaW[ci1], u2 = eaW[ci2], u3 = eaW[ci3];
        unsigned xrp = isA ? xruA : xruB;
        float xr0 = up_lo(xrp), xr1 = up_hi(xrp);
        float x00 = up_lo(t0), x01 = up_hi(t0);
        float x10 = up_lo(t1), x11 = up_hi(t1);
        float x20 = up_lo(t2), x21 = up_hi(t2);
        float x30 = up_lo(t3), x31 = up_hi(t3);
        float m00 = x00 + xr0 + ep8u(u0, w0);
        float m01 = x01 + xr1 + ep8u(u0, w1);
        float m10 = x10 + xr0 + ep8u(u1, w0);
        float m11 = x11 + xr1 + ep8u(u1, w1);
        float m20 = x20 + xr0 + ep8u(u2, w0);
        float m21 = x21 + xr1 + ep8u(u2, w1);
        float m30 = x30 + xr0 + ep8u(u3, w0);
        float m31 = x31 + xr1 + ep8u(u3, w1);
        m00 = (m00 > 0.f) ? m00 : 0.2f * m00;
        m01 = (m01 > 0.f) ? m01 : 0.2f * m01;
        m10 = (m10 > 0.f) ? m10 : 0.2f * m10;
        m11 = (m11 > 0.f) ? m11 : 0.2f * m11;
        m20 = (m20 > 0.f) ? m20 : 0.2f * m20;
        m21 = (m21 > 0.f) ? m21 : 0.2f * m21;
        m30 = (m30 > 0.f) ? m30 : 0.2f * m30;
        m31 = (m31 > 0.f) ? m31 : 0.2f * m31;
        float p0 = fmaf(m00, attv.x, m01 * attv.y);
        float p1 = fmaf(m10, attv.x, m11 * attv.y);
        float p2 = fmaf(m20, attv.x, m21 * attv.y);
        float p3 = fmaf(m30, attv.x, m31 * attv.y);
        p0 = row_reduce16(p0);
        p1 = row_reduce16(p1);
        p2 = row_reduce16(p2);
        p3 = row_reduce16(p3);
        float e0v = __expf(p0), e1v = __expf(p1), e2v = __expf(p2), e3v = __expf(p3);
        if (j + 1 >= cnt) e1v = 0.f;
        if (j + 2 >= cnt) e2v = 0.f;
        if (j + 3 >= cnt) e3v = 0.f;
        if (isA) {
          accA0 = fmaf(e0v, x00, accA0); accA1 = fmaf(e0v, x01, accA1);
          accA0 = fmaf(e1v, x10, accA0); accA1 = fmaf(e1v, x11, accA1);
          accA0 = fmaf(e2v, x20, accA0); accA1 = fmaf(e2v, x21, accA1);
          accA0 = fmaf(e3v, x30, accA0); accA1 = fmaf(e3v, x31, accA1);
          denA += (e0v + e1v) + (e2v + e3v);
        } else {
          accB0 = fmaf(e0v, x00, accB0); accB1 = fmaf(e0v, x01, accB1);
          accB0 = fmaf(e1v, x10, accB0); accB1 = fmaf(e1v, x11, accB1);
          accB0 = fmaf(e2v, x20, accB0); accB1 = fmaf(e2v, x21, accB1);
          accB0 = fmaf(e3v, x30, accB0); accB1 = fmaf(e3v, x31, accB1);
          denB += (e0v + e1v) + (e2v + e3v);
        }
      }
      float invA = 1.f / (denA + 1e-16f);
      float invB = 1.f / (denB + 1e-16f);
      hA0 = accA0 * invA + cbv.x; hA1 = accA1 * invA + cbv.y;
      hB0 = accB0 * invB + cbv.x; hB1 = accB1 * invB + cbv.y;
    } else {
      // rare fallback: pair window exceeds 64 edges -> r12 solo path per node
      float accA0 = 0.f, accA1 = 0.f, denA = 0.f;
      float accB0 = 0.f, accB1 = 0.f, denB = 0.f;
      solo_node(e0A, e1A, l, esrc, xlb, eas4, up_lo(xruA), up_hi(xruA),
                w0, w1, attv, accA0, accA1, denA);
      solo_node(e1A, e1B, l, esrc, xlb, eas4, up_lo(xruB), up_hi(xruB),
                w0, w1, attv, accB0, accB1, denB);
      float invA = 1.f / (denA + 1e-16f);
      float invB = 1.f / (denB + 1e-16f);
      hA0 = accA0 * invA + cbv.x; hA1 = accA1 * invA + cbv.y;
      hB0 = accB0 * invB + cbv.x; hB1 = accB1 * invB + cbv.y;
    }
    *(float2*)&buf[(size_t)nA * H_ + c0] = make_float2(hA0, hA1);
    *(float2*)&buf[(size_t)nB * H_ + c0] = make_float2(hB0, hB1);
    a1_0 += hA0 + hB0; a1_1 += hA1 + hB1;
    a2_0 = fmaf(hA0, hA0, a2_0); a2_0 = fmaf(hB0, hB0, a2_0);
    a2_1 = fmaf(hA1, hA1, a2_1); a2_1 = fmaf(hB1, hB1, a2_1);
  }
  sA[t] = a1_0; sB[t] = a1_1; sC[t] = a2_0; sD[t] = a2_1;
  __syncthreads();
  if (t < 64) {
    float r1 = sA[t] + sA[t + 64] + sA[t + 128] + sA[t + 192];
    float r2 = sB[t] + sB[t + 64] + sB[t + 128] + sB[t + 192];
    float r3 = sC[t] + sC[t + 64] + sC[t + 128] + sC[t + 192];
    float r4 = sD[t] + sD[t + 64] + sD[t + 128] + sD[t + 192];
    atomicAdd(&ssum[2 * t], r1);
    atomicAdd(&ssum[2 * t + 1], r2);
    atomicAdd(&ssq[2 * t], r3);
    atomicAdd(&ssq[2 * t + 1], r4);
  }
}

// ---------------- BN apply with inline finalize ----------------
__global__ __launch_bounds__(256) void apply_bn_relu(const float* __restrict__ y,
                                                     float* __restrict__ out,
                                                     const float* __restrict__ g,
                                                     const float* __restrict__ beta,
                                                     const float* __restrict__ ssum,
                                                     const float* __restrict__ ssq,
                                                     float rows_inv,
                                                     long total, int cmask) {
  long i = (long)blockIdx.x * 256 + threadIdx.x;
  if (i >= total) return;
  int c = (int)i & cmask;
  float m = ssum[c] * rows_inv;
  float rs = rsqrtf(ssq[c] * rows_inv - m * m + 1e-5f);
  float v = g[c] * (y[i] - m) * rs + beta[c];
  out[i] = fmaxf(v, 0.f);
}

// ---------------- pooling with fused layer-2 residual (inline BN finalize) ----
__global__ __launch_bounds__(128) void pool_residual(const int* __restrict__ goff,
                                                     const float* __restrict__ xn,
                                                     const float* __restrict__ buf,
                                                     const float* __restrict__ g,
                                                     const float* __restrict__ beta,
                                                     const float* __restrict__ ssum,
                                                     const float* __restrict__ ssq,
                                                     float rows_inv,
                                                     float* __restrict__ xg) {
  int gr = blockIdx.x;
  int t = threadIdx.x;
  int n0 = goff[gr], n1 = goff[gr + 1];
  float mm = ssum[t] * rows_inv;
  float rr = rsqrtf(ssq[t] * rows_inv - mm * mm + 1e-5f);
  float gg = g[t], bb = beta[t];
  float s = 0.f, mx = -INFINITY;
  for (int n = n0; n < n1; n++) {
    float w = gg * (buf[(size_t)n * H_ + t] - mm) * rr + bb;
    w = (w > 0.f) ? w : (__expf(w) - 1.f);
    float v = xn[(size_t)n * H_ + t] + w;
    s += v;
    mx = fmaxf(mx, v);
  }
  float c = (float)(n1 - n0);
  xg[gr * 384 + t] = s / fmaxf(c, 1.f);
  xg[gr * 384 + 128 + t] = (c > 0.f) ? mx : 0.f;
  xg[gr * 384 + 256 + t] = s;
}

// ---------------- MLP GEMMs (fused colstats) ----------------
template <int K, int COLS>
__global__ void mlp_gemm(const float* __restrict__ A, const float* __restrict__ W,
                         const float* __restrict__ b, float* __restrict__ Y, int rows,
                         float* __restrict__ ssum, float* __restrict__ ssq) {
  __shared__ float xs[8][K];
  int t = threadIdx.x;
  int row0 = blockIdx.x * 8;
  for (int i = t; i < 8 * K; i += COLS) {
    int r = i / K, k = i % K;
    int row = row0 + r;
    xs[r][k] = (row < rows) ? A[row * K + k] : 0.f;
  }
  __syncthreads();
  float acc[8];
#pragma unroll
  for (int r = 0; r < 8; r++) acc[r] = 0.f;
  for (int k = 0; k < K; k++) {
    float w = W[k * COLS + t];
#pragma unroll
    for (int r = 0; r < 8; r++) acc[r] = fmaf(xs[r][k], w, acc[r]);
  }
  float bb = b[t];
  float a1 = 0.f, a2 = 0.f;
#pragma unroll
  for (int r = 0; r < 8; r++) {
    int row = row0 + r;
    if (row < rows) {
      float v = acc[r] + bb;
      Y[row * COLS + t] = v;
      a1 += v;
      a2 = fmaf(v, v, a2);
    }
  }
  atomicAdd(&ssum[t], a1);
  atomicAdd(&ssq[t], a2);
}

// ---------------- head ----------------
__global__ __launch_bounds__(64) void head_kernel(const float* __restrict__ u,
                                                  const float* __restrict__ W,
                                                  const float* __restrict__ b,
                                                  float* __restrict__ out) {
  __shared__ float row[128];
  int g = blockIdx.x;
  int t = threadIdx.x;
  row[t] = u[g * 128 + t];
  row[t + 64] = u[g * 128 + 64 + t];
  __syncthreads();
  if (t < 12) {
    float acc = b[t];
    for (int k = 0; k < 128; k++) acc = fmaf(row[k], W[k * 12 + t], acc);
    out[g * 12 + t] = 1.f / (1.f + expf(-acc));
  }
}

// ---------------- launcher ----------------
extern "C" void kernel_launch(void* const* d_in, const int* in_sizes, int n_in, void* d_out,
                              int out_size, void* d_ws, size_t ws_size, hipStream_t stream) {
  (void)in_sizes; (void)n_in; (void)out_size; (void)ws_size;
  const float* x       = (const float*)d_in[0];
  const int*   ei      = (const int*)d_in[1];
  const float* ea      = (const float*)d_in[2];
  const int*   batch   = (const int*)d_in[3];
  const float* in_W    = (const float*)d_in[4];
  const float* in_b    = (const float*)d_in[5];
  const float* in_g    = (const float*)d_in[6];
  const float* in_beta = (const float*)d_in[7];
  const float* Wl      = (const float*)d_in[8];
  const float* Wr      = (const float*)d_in[9];
  const float* We      = (const float*)d_in[10];
  const float* att     = (const float*)d_in[11];
  const float* conv_b  = (const float*)d_in[12];
  const float* bn_g    = (const float*)d_in[13];
  const float* bn_b    = (const float*)d_in[14];
  const float* t1_W    = (const float*)d_in[15];
  const float* t1_b    = (const float*)d_in[16];
  const float* t1_g    = (const float*)d_in[17];
  const float* t1_beta = (const float*)d_in[18];
  const float* t2_W    = (const float*)d_in[19];
  const float* t2_b    = (const float*)d_in[20];
  const float* t2_g    = (const float*)d_in[21];
  const float* t2_beta = (const float*)d_in[22];
  const float* head_W  = (const float*)d_in[23];
  const float* head_b  = (const float*)d_in[24];
  float* out = (float*)d_out;

  float* p = (float*)d_ws;
  float* xn    = p; p += N_ * H_;
  float* buf   = p; p += N_ * H_;
  float* sstat = p; p += 6 * 512;   // 6 stages x (ssum 256 | ssq 256)
  float* xg    = p; p += G_ * 384;
  float* u1    = p; p += G_ * 256;
  float* u2    = p; p += G_ * 128;
  unsigned* up = (unsigned*)p;
  unsigned* xlb  = up; up += (size_t)N_ * 64;
  unsigned* xrb  = up; up += (size_t)N_ * 64;
  unsigned* easb = up; up += (size_t)E_ * 4;
  unsigned short* wpack = (unsigned short*)up; up += 3 * 32768 / 2;
  int* ip = (int*)up;
  int* deg    = ip; ip += N_;
  int* eoff   = ip; ip += N_ + 1;
  int* cursor = ip; ip += N_;
  int* goff   = ip; ip += G_ + 1;
  int* esrc   = ip; ip += E_;
  int* bsum   = ip; ip += 64;
  int* boff   = ip; ip += 64;

#define SSUM(s) (sstat + (s) * 512)
#define SSQ(s)  (sstat + (s) * 512 + 256)

  // ---- build CSR structures + pre-pack weights ----
  hipMemsetAsync(deg, 0, (size_t)N_ * sizeof(int), stream);
  hipMemsetAsync(sstat, 0, 6 * 512 * sizeof(float), stream);
  hist_kernel<<<1024, 256, 0, stream>>>(ei + E_, E_, deg);
  scan_local<<<49, 1024, 0, stream>>>(deg, eoff, bsum, N_);
  scan_bsum<<<1, 64, 0, stream>>>(bsum, boff, 49);
  scan_add<<<49, 1024, 0, stream>>>(eoff, boff, cursor, N_);
  edge_scatter<<<(E_ + 255) / 256, 256, 0, stream>>>(ei, ea, cursor, esrc, easb);
  goff_from_sorted<<<(N_ + 255) / 256, 256, 0, stream>>>(batch, goff);
  pack_weights<<<384, 256, 0, stream>>>(Wl, Wr, wpack);

  // ---- input layer (stats -> stage 0) ----
  in_gemm<<<(N_ + 31) / 32, 256, 0, stream>>>(x, in_W, in_b, buf, SSUM(0), SSQ(0));

  // ---- 3 GATv2 layers (conv stats of layer l -> stage l+1) ----
  const float rnInv = 1.f / N_;
  for (int l = 0; l < 3; l++) {
    if (l == 0) {
      gemm_mfma<1><<<782, 256, 0, stream>>>(xn, buf, in_g, in_beta, SSUM(0), SSQ(0), rnInv,
                                            wpack + (size_t)l * 32768, xlb, xrb);
    } else {
      gemm_mfma<2><<<782, 256, 0, stream>>>(xn, buf, bn_g + (l - 1) * H_, bn_b + (l - 1) * H_,
                                            SSUM(l), SSQ(l), rnInv,
                                            wpack + (size_t)l * 32768, xlb, xrb);
    }
    agg_csr<<<2048, 256, 0, stream>>>(eoff, esrc, easb, We + l * 8 * H_, att + l * H_,
                                      xlb, xrb, conv_b + l * H_, buf, SSUM(l + 1), SSQ(l + 1));
  }

  // ---- pooling with fused layer-2 residual (stage 3 stats) ----
  pool_residual<<<G_, 128, 0, stream>>>(goff, xn, buf, bn_g + 2 * H_, bn_b + 2 * H_,
                                        SSUM(3), SSQ(3), rnInv, xg);

  // ---- t1 (stats -> stage 4) ----
  const float rgInv = 1.f / G_;
  mlp_gemm<384, 256><<<G_ / 8, 256, 0, stream>>>(xg, t1_W, t1_b, u1, G_, SSUM(4), SSQ(4));
  apply_bn_relu<<<(G_ * 256 + 255) / 256, 256, 0, stream>>>(u1, u1, t1_g, t1_beta,
                                                            SSUM(4), SSQ(4), rgInv,
                                                            (long)G_ * 256, 255);

  // ---- t2 (stats -> stage 5) ----
  mlp_gemm<256, 128><<<G_ / 8, 128, 0, stream>>>(u1, t2_W, t2_b, u2, G_, SSUM(5), SSQ(5));
  apply_bn_relu<<<(G_ * 128 + 255) / 256, 256, 0, stream>>>(u2, u2, t2_g, t2_beta,
                                                            SSUM(5), SSQ(5), rgInv,
                                                            (long)G_ * 128, 127);

  // ---- head ----
  head_kernel<<<G_, 64, 0, stream>>>(u2, head_W, head_b, out);
#undef SSUM
#undef SSQ
}

// Round 6
// 841.120 us; speedup vs baseline: 1.0362x; 1.0003x over previous
//
#include <hip/hip_runtime.h>
#include <math.h>

// ToxicityGATv2 — round 15: dispatch-count reduction (21 -> 14).
//  * prep_kernel: hist + goff + pack_weights + in_gemm merged (block-range branch)
//  * scan_onepass: single-pass chained scan (49 co-resident blocks, atomic
//    publish with +1 sentinel, zero-init) replaces scan_local/bsum/add
//  * apply_bn_relu fused into mlp2 staging and head staging
//  * single memset (sstat|deg|pref contiguous in ws)
// agg_csr (r14 paired-pipeline, at its random-fill throughput floor ~680 GB/s)
// and gemm_mfma bodies unchanged.

constexpr int N_ = 50000;
constexpr int E_ = 400000;
constexpr int G_ = 2000;
constexpr int H_ = 128;
constexpr int IN_ = 39;

constexpr int HIST_B = 1024;
constexpr int GOFF_B = (N_ + 255) / 256;      // 196
constexpr int PACK_B = 384;
constexpr int INGEMM_B = (N_ + 31) / 32;      // 1563

typedef __attribute__((ext_vector_type(8))) short bf16x8;
typedef __attribute__((ext_vector_type(4))) float f32x4;

// ---------------- bf16 pack/unpack (RNE) ----------------
__device__ __forceinline__ unsigned pk_bf16(float a, float b) {
  unsigned ua = __float_as_uint(a);
  unsigned ub = __float_as_uint(b);
  ua = (ua + 0x7fffu + ((ua >> 16) & 1u)) >> 16;
  ub = (ub + 0x7fffu + ((ub >> 16) & 1u)) & 0xffff0000u;
  return ua | ub;
}
__device__ __forceinline__ unsigned short bf16_1(float x) {
  unsigned u = __float_as_uint(x);
  u = (u + 0x7fffu + ((u >> 16) & 1u)) >> 16;
  return (unsigned short)u;
}
__device__ __forceinline__ float up_lo(unsigned u) { return __uint_as_float(u << 16); }
__device__ __forceinline__ float up_hi(unsigned u) { return __uint_as_float(u & 0xffff0000u); }

// ---------------- DPP rotate-reduce over 16-lane rows (VALU pipe, no LDS) ----
template <int CTRL>
__device__ __forceinline__ float dpp_radd(float x) {
  int y = __builtin_amdgcn_update_dpp(0, __float_as_int(x), CTRL, 0xF, 0xF, false);
  return x + __int_as_float(y);
}
__device__ __forceinline__ float row_reduce16(float p) {
  p = dpp_radd<0x121>(p);  // row_ror:1
  p = dpp_radd<0x122>(p);  // row_ror:2
  p = dpp_radd<0x124>(p);  // row_ror:4
  p = dpp_radd<0x128>(p);  // row_ror:8
  return p;
}

// ---------------- merged prep: hist | goff | pack_weights | in_gemm ----------
__global__ __launch_bounds__(256) void prep_kernel(const int* __restrict__ ei,
                                                   const int* __restrict__ batch,
                                                   const float* __restrict__ Wl,
                                                   const float* __restrict__ Wr,
                                                   const float* __restrict__ x,
                                                   const float* __restrict__ in_W,
                                                   const float* __restrict__ in_b,
                                                   int* __restrict__ deg,
                                                   int* __restrict__ goff,
                                                   unsigned short* __restrict__ wpack,
                                                   float* __restrict__ y,
                                                   float* __restrict__ ssum,
                                                   float* __restrict__ ssq) {
  int b = blockIdx.x;
  int t = threadIdx.x;
  if (b < HIST_B) {
    for (int i = b * 256 + t; i < E_; i += HIST_B * 256)
      atomicAdd(&deg[ei[E_ + i]], 1);
    return;
  }
  b -= HIST_B;
  if (b < GOFF_B) {
    int i = b * 256 + t;
    if (i >= N_) return;
    int bi = batch[i];
    int bp = (i == 0) ? -1 : batch[i - 1];
    for (int g = bp + 1; g <= bi; g++) goff[g] = i;
    if (i == N_ - 1) {
      for (int g = bi + 1; g <= G_; g++) goff[g] = N_;
    }
    return;
  }
  b -= GOFF_B;
  if (b < PACK_B) {
    int i = b * 256 + t;
    if (i >= 3 * 128 * 256) return;
    int l = i >> 15;
    int rem = i & 32767;
    int k = rem >> 8;
    int n = rem & 255;
    const float* Wsrc = (n < 128) ? (Wl + l * H_ * H_) : (Wr + l * H_ * H_);
    int nn = n & 127;
    wpack[(size_t)l * 32768 + n * 128 + k] = bf16_1(Wsrc[k * H_ + nn]);
    return;
  }
  b -= PACK_B;
  // ---- in_gemm body ----
  __shared__ float xs[32][40];
  __shared__ float s1[256], s2[256];
  int row0 = b * 32;
  for (int i = t; i < 32 * IN_; i += 256) {
    int r = i / IN_, k = i % IN_;
    int row = row0 + r;
    xs[r][k] = (row < N_) ? x[row * IN_ + k] : 0.f;
  }
  __syncthreads();
  int col = t & 127;
  int half = t >> 7;
  float acc[16];
#pragma unroll
  for (int r = 0; r < 16; r++) acc[r] = 0.f;
  for (int k = 0; k < IN_; k++) {
    float w = in_W[k * H_ + col];
#pragma unroll
    for (int r = 0; r < 16; r++) acc[r] = fmaf(xs[half * 16 + r][k], w, acc[r]);
  }
  float bb = in_b[col];
  float a1 = 0.f, a2 = 0.f;
#pragma unroll
  for (int r = 0; r < 16; r++) {
    int row = row0 + half * 16 + r;
    float v = acc[r] + bb;
    if (row < N_) {
      y[row * H_ + col] = v;
      a1 += v;
      a2 = fmaf(v, v, a2);
    }
  }
  s1[t] = a1; s2[t] = a2;
  __syncthreads();
  if (t < 128) {
    atomicAdd(&ssum[t], s1[t] + s1[t + 128]);
    atomicAdd(&ssq[t], s2[t] + s2[t + 128]);
  }
}

// ---------------- single-pass chained scan (49 co-resident blocks) ----------
__global__ __launch_bounds__(1024) void scan_onepass(const int* __restrict__ deg,
                                                     int* __restrict__ eoff,
                                                     int* __restrict__ cursor,
                                                     int* __restrict__ pref, int n) {
  __shared__ int wsum[16];
  __shared__ int sbase;
  int t = threadIdx.x, lane = t & 63, wid = t >> 6;
  int b = blockIdx.x;
  int idx = b * 1024 + t;
  int v = (idx < n) ? deg[idx] : 0;
  int x = v;
#pragma unroll
  for (int off = 1; off < 64; off <<= 1) {
    int y = __shfl_up(x, off, 64);
    if (lane >= off) x += y;
  }
  if (lane == 63) wsum[wid] = x;
  __syncthreads();
  if (t == 0) {
    int acc = 0;
#pragma unroll
    for (int w = 0; w < 16; w++) { int tmp = wsum[w]; wsum[w] = acc; acc += tmp; }
    int prev = 0;
    if (b > 0) {
      int got;
      do { got = atomicAdd(&pref[b - 1], 0); } while (got == 0);  // +1 sentinel
      prev = got - 1;
    }
    atomicExch(&pref[b], prev + acc + 1);
    sbase = prev;
  }
  __syncthreads();
  if (idx < n) {
    int e = sbase + wsum[wid] + x - v;
    eoff[idx] = e;
    cursor[idx] = e;
    if (idx == n - 1) eoff[n] = E_;
  }
}

// ---------------- edge scatter (bf16 attrs) ----------------
__global__ __launch_bounds__(256) void edge_scatter(const int* __restrict__ ei,
                                                    const float* __restrict__ ea,
                                                    int* __restrict__ cursor,
                                                    int* __restrict__ esrc,
                                                    unsigned* __restrict__ easb) {
  int e = blockIdx.x * 256 + threadIdx.x;
  if (e >= E_) return;
  int src = ei[e];
  int dst = ei[E_ + e];
  int j = atomicAdd(&cursor[dst], 1);
  esrc[j] = src;
  const float4* eav = (const float4*)(ea + (size_t)e * 8);
  float4 a0 = eav[0], a1 = eav[1];
  uint4 o;
  o.x = pk_bf16(a0.x, a0.y);
  o.y = pk_bf16(a0.z, a0.w);
  o.z = pk_bf16(a1.x, a1.y);
  o.w = pk_bf16(a1.z, a1.w);
  ((uint4*)easb)[j] = o;
}

// ---------------- MFMA node GEMM (pre-packed bf16 B) ----------
// MODE 1: v=relu(bn(buf)); xn=v.  MODE 2: v=xn+elu(bn(buf)); xn=v.
template <int MODE>
__global__ __launch_bounds__(256) void gemm_mfma(float* __restrict__ xn,
                                                 const float* __restrict__ buf,
                                                 const float* __restrict__ g,
                                                 const float* __restrict__ beta,
                                                 const float* __restrict__ ssum,
                                                 const float* __restrict__ ssq,
                                                 float rows_inv,
                                                 const unsigned short* __restrict__ wp,
                                                 unsigned* __restrict__ xlb,
                                                 unsigned* __restrict__ xrb) {
  __shared__ char smem[17408 + 20480];
  short (*a_s)[136] = (short(*)[136])smem;              // 64 rows x 128 k (pad 136)
  short (*b_s)[40] = (short(*)[40])(smem + 17408);      // 256 n x 32 k (pad 40)
  float* t2base = (float*)(smem + 17408);               // epilogue reuse
  int t = threadIdx.x;
  int lane = t & 63, w = t >> 6;
  int quad = lane >> 4, lc = lane & 15;
  int row0 = blockIdx.x * 64;

  // ---- stage A (fused BN epilogue, fp32 xn updated, bf16 into LDS) ----
  {
    int r = t >> 2;
    int row = row0 + r;
    int kb0 = (t & 3) * 32;
    bool valid = row < N_;
    for (int kk = 0; kk < 32; kk += 4) {
      int c = kb0 + kk;
      float4 v = make_float4(0.f, 0.f, 0.f, 0.f);
      if (valid) {
        float4 bv = *(const float4*)&buf[(size_t)row * H_ + c];
        float4 gv = *(const float4*)&g[c];
        float4 be = *(const float4*)&beta[c];
        float4 s1 = *(const float4*)&ssum[c];
        float4 s2 = *(const float4*)&ssq[c];
        float m0 = s1.x * rows_inv, m1 = s1.y * rows_inv, m2 = s1.z * rows_inv, m3 = s1.w * rows_inv;
        float r0 = rsqrtf(s2.x * rows_inv - m0 * m0 + 1e-5f);
        float r1 = rsqrtf(s2.y * rows_inv - m1 * m1 + 1e-5f);
        float r2 = rsqrtf(s2.z * rows_inv - m2 * m2 + 1e-5f);
        float r3 = rsqrtf(s2.w * rows_inv - m3 * m3 + 1e-5f);
        float t0 = gv.x * (bv.x - m0) * r0 + be.x;
        float t1 = gv.y * (bv.y - m1) * r1 + be.y;
        float t2 = gv.z * (bv.z - m2) * r2 + be.z;
        float t3 = gv.w * (bv.w - m3) * r3 + be.w;
        if (MODE == 1) {
          v = make_float4(fmaxf(t0, 0.f), fmaxf(t1, 0.f), fmaxf(t2, 0.f), fmaxf(t3, 0.f));
        } else {
          float4 xo = *(const float4*)&xn[(size_t)row * H_ + c];
          v.x = xo.x + ((t0 > 0.f) ? t0 : (__expf(t0) - 1.f));
          v.y = xo.y + ((t1 > 0.f) ? t1 : (__expf(t1) - 1.f));
          v.z = xo.z + ((t2 > 0.f) ? t2 : (__expf(t2) - 1.f));
          v.w = xo.w + ((t3 > 0.f) ? t3 : (__expf(t3) - 1.f));
        }
        *(float4*)&xn[(size_t)row * H_ + c] = v;
      }
      uint2 pk;
      pk.x = pk_bf16(v.x, v.y);
      pk.y = pk_bf16(v.z, v.w);
      *(uint2*)&a_s[r][c] = pk;
    }
  }

  f32x4 acc[16];
#pragma unroll
  for (int nt = 0; nt < 16; nt++) acc[nt] = (f32x4){0.f, 0.f, 0.f, 0.f};

  for (int kb = 0; kb < 4; kb++) {
    __syncthreads();
    // stage B chunk: vectorized copy from pre-packed weights (16 KB)
    for (int i = t; i < 1024; i += 256) {
      int n = i >> 2;
      int k8 = (i & 3) * 8;
      *(uint4*)&b_s[n][k8] = *(const uint4*)&wp[(size_t)n * 128 + kb * 32 + k8];
    }
    __syncthreads();
    bf16x8 av = *(const bf16x8*)&a_s[w * 16 + lc][kb * 32 + quad * 8];
#pragma unroll
    for (int nt = 0; nt < 16; nt++) {
      bf16x8 bv = *(const bf16x8*)&b_s[nt * 16 + lc][quad * 8];
      acc[nt] = __builtin_amdgcn_mfma_f32_16x16x32_bf16(av, bv, acc[nt], 0, 0, 0);
    }
  }
  __syncthreads();  // b_s -> t2 reuse

  // ---- epilogue: transpose 16x32 chunks via LDS, packed coalesced stores ----
  float* t2 = t2base + w * 544;  // 16 rows x 34 cols fp32, per-wave private
  for (int ntp = 0; ntp < 8; ntp++) {
#pragma unroll
    for (int rr = 0; rr < 4; rr++) {
      t2[(quad * 4 + rr) * 34 + lc] = acc[2 * ntp][rr];
      t2[(quad * 4 + rr) * 34 + 16 + lc] = acc[2 * ntp + 1][rr];
    }
    __asm__ volatile("s_waitcnt lgkmcnt(0)" ::: "memory");
#pragma unroll
    for (int it = 0; it < 4; it++) {
      int item = lane + it * 64;
      int p = item & 15, rowi = item >> 4;
      float v0 = t2[rowi * 34 + 2 * p];
      float v1 = t2[rowi * 34 + 2 * p + 1];
      unsigned u = pk_bf16(v0, v1);
      int colpair = ntp * 16 + p;
      int rowg = row0 + w * 16 + rowi;
      if (rowg < N_) {
        if (colpair < 64) xlb[(size_t)rowg * 64 + colpair] = u;
        else xrb[(size_t)rowg * 64 + colpair - 64] = u;
      }
    }
    __asm__ volatile("s_waitcnt lgkmcnt(0)" ::: "memory");
  }
}

// ---------------- CSR aggregation (r14 paired-pipeline body) ----------------
__device__ __forceinline__ float ep8u(const uint4& u, const float* w) {
  float ep = up_lo(u.x) * w[0];
  ep = fmaf(up_hi(u.x), w[1], ep);
  ep = fmaf(up_lo(u.y), w[2], ep);
  ep = fmaf(up_hi(u.y), w[3], ep);
  ep = fmaf(up_lo(u.z), w[4], ep);
  ep = fmaf(up_hi(u.z), w[5], ep);
  ep = fmaf(up_lo(u.w), w[6], ep);
  ep = fmaf(up_hi(u.w), w[7], ep);
  return ep;
}

template <bool MASK>
__device__ __forceinline__ void pack4(int spre, int j, int cnt, int base, int l,
                                      const unsigned* __restrict__ xlb,
                                      const uint4* __restrict__ eas4,
                                      float xr0, float xr1,
                                      const float* w0, const float* w1,
                                      float2 attv,
                                      float& acc0, float& acc1, float& den) {
  int i0 = j;
  int i1 = j + 1, i2 = j + 2, i3 = j + 3;
  if (MASK) {
    i1 = (i1 < cnt) ? i1 : cnt - 1;
    i2 = (i2 < cnt) ? i2 : cnt - 1;
    i3 = (i3 < cnt) ? i3 : cnt - 1;
  }
  int s0 = __builtin_amdgcn_readlane(spre, i0);
  int s1 = __builtin_amdgcn_readlane(spre, i1);
  int s2 = __builtin_amdgcn_readlane(spre, i2);
  int s3 = __builtin_amdgcn_readlane(spre, i3);
  unsigned xu0 = xlb[(size_t)s0 * 64 + l];
  unsigned xu1 = xlb[(size_t)s1 * 64 + l];
  unsigned xu2 = xlb[(size_t)s2 * 64 + l];
  unsigned xu3 = xlb[(size_t)s3 * 64 + l];
  uint4 u0 = eas4[base + i0];
  uint4 u1 = eas4[base + i1];
  uint4 u2 = eas4[base + i2];
  uint4 u3 = eas4[base + i3];
  float x00 = up_lo(xu0), x01 = up_hi(xu0);
  float x10 = up_lo(xu1), x11 = up_hi(xu1);
  float x20 = up_lo(xu2), x21 = up_hi(xu2);
  float x30 = up_lo(xu3), x31 = up_hi(xu3);
  float m00 = x00 + xr0 + ep8u(u0, w0);
  float m01 = x01 + xr1 + ep8u(u0, w1);
  float m10 = x10 + xr0 + ep8u(u1, w0);
  float m11 = x11 + xr1 + ep8u(u1, w1);
  float m20 = x20 + xr0 + ep8u(u2, w0);
  float m21 = x21 + xr1 + ep8u(u2, w1);
  float m30 = x30 + xr0 + ep8u(u3, w0);
  float m31 = x31 + xr1 + ep8u(u3, w1);
  m00 = (m00 > 0.f) ? m00 : 0.2f * m00;
  m01 = (m01 > 0.f) ? m01 : 0.2f * m01;
  m10 = (m10 > 0.f) ? m10 : 0.2f * m10;
  m11 = (m11 > 0.f) ? m11 : 0.2f * m11;
  m20 = (m20 > 0.f) ? m20 : 0.2f * m20;
  m21 = (m21 > 0.f) ? m21 : 0.2f * m21;
  m30 = (m30 > 0.f) ? m30 : 0.2f * m30;
  m31 = (m31 > 0.f) ? m31 : 0.2f * m31;
  float p0 = fmaf(m00, attv.x, m01 * attv.y);
  float p1 = fmaf(m10, attv.x, m11 * attv.y);
  float p2 = fmaf(m20, attv.x, m21 * attv.y);
  float p3 = fmaf(m30, attv.x, m31 * attv.y);
  p0 = row_reduce16(p0);
  p1 = row_reduce16(p1);
  p2 = row_reduce16(p2);
  p3 = row_reduce16(p3);
  float e0v = __expf(p0), e1v = __expf(p1), e2v = __expf(p2), e3v = __expf(p3);
  if (MASK) {
    if (j + 1 >= cnt) e1v = 0.f;
    if (j + 2 >= cnt) e2v = 0.f;
    if (j + 3 >= cnt) e3v = 0.f;
  }
  acc0 = fmaf(e0v, x00, acc0); acc1 = fmaf(e0v, x01, acc1);
  acc0 = fmaf(e1v, x10, acc0); acc1 = fmaf(e1v, x11, acc1);
  acc0 = fmaf(e2v, x20, acc0); acc1 = fmaf(e2v, x21, acc1);
  acc0 = fmaf(e3v, x30, acc0); acc1 = fmaf(e3v, x31, acc1);
  den += (e0v + e1v) + (e2v + e3v);
}

__device__ __forceinline__ void solo_node(int e0, int e1, int l,
                                          const int* __restrict__ esrc,
                                          const unsigned* __restrict__ xlb,
                                          const uint4* __restrict__ eas4,
                                          float xr0, float xr1,
                                          const float* w0, const float* w1,
                                          float2 attv,
                                          float& acc0, float& acc1, float& den) {
  for (int base = e0; base < e1; base += 64) {
    int cnt = min(64, e1 - base);
    int spre = (base + l < e1) ? esrc[base + l] : 0;
    int j = 0;
    for (; j + 4 <= cnt; j += 4)
      pack4<false>(spre, j, cnt, base, l, xlb, eas4, xr0, xr1, w0, w1, attv, acc0, acc1, den);
    if (j < cnt)
      pack4<true>(spre, j, cnt, base, l, xlb, eas4, xr0, xr1, w0, w1, attv, acc0, acc1, den);
  }
}

__global__ __launch_bounds__(256) void agg_csr(const int* __restrict__ eoff,
                                               const int* __restrict__ esrc,
                                               const unsigned* __restrict__ easb,
                                               const float* __restrict__ Wel,
                                               const float* __restrict__ attl,
                                               const unsigned* __restrict__ xlb,
                                               const unsigned* __restrict__ xrb,
                                               const float* __restrict__ cb,
                                               float* __restrict__ buf,
                                               float* __restrict__ ssum,
                                               float* __restrict__ ssq) {
  __shared__ float sA[256], sB[256], sC[256], sD[256];
  __shared__ uint4 eaLds[4][64];   // per-wave attr window (1 KB each)
  int t = threadIdx.x;
  int l = t & 63;
  int sub = t >> 6;
  int c0 = l * 2;
  uint4* eaW = &eaLds[sub][0];
  float w0[8], w1[8];
#pragma unroll
  for (int k = 0; k < 8; k++) {
    float2 wv = *(const float2*)&Wel[k * H_ + c0];
    w0[k] = wv.x; w1[k] = wv.y;
  }
  float2 attv = *(const float2*)&attl[c0];
  float2 cbv = *(const float2*)&cb[c0];
  const uint4* eas4 = (const uint4*)easb;
  float a1_0 = 0.f, a1_1 = 0.f, a2_0 = 0.f, a2_1 = 0.f;

  for (int pi = blockIdx.x * 4 + sub; pi < N_ / 2; pi += gridDim.x * 4) {
    int nA = 2 * pi, nB = nA + 1;
    int e0A = eoff[nA], e1A = eoff[nA + 1], e1B = eoff[nA + 2];
    unsigned xruA = xrb[(size_t)nA * 64 + l];
    unsigned xruB = xrb[(size_t)nB * 64 + l];
    int cE = e1B - e0A;
    float hA0, hA1, hB0, hB1;
    if (cE <= 64) {
      int cA = e1A - e0A, cB = e1B - e1A;
      // stage pair attrs to LDS (one coalesced load) + esrc chunk to lane reg
      if (l < cE) eaW[l] = eas4[e0A + l];
      int spre = (l < cE) ? esrc[e0A + l] : 0;
      __asm__ volatile("s_waitcnt lgkmcnt(0)" ::: "memory");
      int nPA = (cA + 3) >> 2;
      int nP = nPA + ((cB + 3) >> 2);
      float accA0 = 0.f, accA1 = 0.f, denA = 0.f;
      float accB0 = 0.f, accB1 = 0.f, denB = 0.f;
      unsigned xu0 = 0, xu1 = 0, xu2 = 0, xu3 = 0;
      int i0 = 0, i1 = 0, i2 = 0, i3 = 0;  // uniform pack indices (local)
      if (nP > 0) {  // prefetch pack 0
        bool isA = 0 < nPA;
        int off = isA ? 0 : cA;
        int cnt = isA ? cA : cB;
        int lim = off + cnt - 1;
        i0 = off;
        i1 = min(off + 1, lim); i2 = min(off + 2, lim); i3 = min(off + 3, lim);
        xu0 = xlb[(size_t)__builtin_amdgcn_readlane(spre, i0) * 64 + l];
        xu1 = xlb[(size_t)__builtin_amdgcn_readlane(spre, i1) * 64 + l];
        xu2 = xlb[(size_t)__builtin_amdgcn_readlane(spre, i2) * 64 + l];
        xu3 = xlb[(size_t)__builtin_amdgcn_readlane(spre, i3) * 64 + l];
      }
      for (int k = 0; k < nP; k++) {
        unsigned t0 = xu0, t1 = xu1, t2 = xu2, t3 = xu3;
        int ci0 = i0, ci1 = i1, ci2 = i2, ci3 = i3;
        bool isA = k < nPA;
        int j = isA ? 4 * k : 4 * (k - nPA);
        int cnt = isA ? cA : cB;
        if (k + 1 < nP) {  // prefetch pack k+1 (gathers only, 4 VGPR)
          bool pA = (k + 1) < nPA;
          int off2 = pA ? 0 : cA;
          int cnt2 = pA ? cA : cB;
          int j2 = pA ? 4 * (k + 1) : 4 * (k + 1 - nPA);
          int b2 = off2 + j2;
          int lim2 = off2 + cnt2 - 1;
          i0 = b2;
          i1 = min(b2 + 1, lim2); i2 = min(b2 + 2, lim2); i3 = min(b2 + 3, lim2);
          xu0 = xlb[(size_t)__builtin_amdgcn_readlane(spre, i0) * 64 + l];
          xu1 = xlb[(size_t)__builtin_amdgcn_readlane(spre, i1) * 64 + l];
          xu2 = xlb[(size_t)__builtin_amdgcn_readlane(spre, i2) * 64 + l];
          xu3 = xlb[(size_t)__builtin_amdgcn_readlane(spre, i3) * 64 + l];
        }
        // attrs from LDS (uniform broadcast reads)
        uint4 u0 = eaW[ci0], u1 = eaW[ci1], u2 = eaW[ci2], u3 = eaW[ci3];
        unsigned xrp = isA ? xruA : xruB;
        float xr0 = up_lo(xrp), xr1 = up_hi(xrp);
        float x00 = up_lo(t0), x01 = up_hi(t0);
        float x10 = up_lo(t1), x11 = up_hi(t1);
        float x20 = up_lo(t2), x21 = up_hi(t2);
        float x30 = up_lo(t3), x31 = up_hi(t3);
        float m00 = x00 + xr0 + ep8u(u0, w0);
        float m01 = x01 + xr1 + ep8u(u0, w1);
        float m10 = x10 + xr0 + ep8u(u1, w0);
        float m11 = x11 + xr1 + ep8u(u1, w1);
        float m20 = x20 + xr0 + ep8u(u2, w0);
        float m21 = x21 + xr1 + ep8u(u2, w1);
        float m30 = x30 + xr0 + ep8u(u3, w0);
        float m31 = x31 + xr1 + ep8u(u3, w1);
        m00 = (m00 > 0.f) ? m00 : 0.2f * m00;
        m01 = (m01 > 0.f) ? m01 : 0.2f * m01;
        m10 = (m10 > 0.f) ? m10 : 0.2f * m10;
        m11 = (m11 > 0.f) ? m11 : 0.2f * m11;
        m20 = (m20 > 0.f) ? m20 : 0.2f * m20;
        m21 = (m21 > 0.f) ? m21 : 0.2f * m21;
        m30 = (m30 > 0.f) ? m30 : 0.2f * m30;
        m31 = (m31 > 0.f) ? m31 : 0.2f * m31;
        float p0 = fmaf(m00, attv.x, m01 * attv.y);
        float p1 = fmaf(m10, attv.x, m11 * attv.y);
        float p2 = fmaf(m20, attv.x, m21 * attv.y);
        float p3 = fmaf(m30, attv.x, m31 * attv.y);
        p0 = row_reduce16(p0);
        p1 = row_reduce16(p1);
        p2 = row_reduce16(p2);
        p3 = row_reduce16(p3);
        float e0v = __expf(p0), e1v = __expf(p1), e2v = __expf(p2), e3v = __expf(p3);
        if (j + 1 >= cnt) e1v = 0.f;
        if (j + 2 >= cnt) e2v = 0.f;
        if (j + 3 >= cnt) e3v = 0.f;
        if (isA) {
          accA0 = fmaf(e0v, x00, accA0); accA1 = fmaf(e0v, x01, accA1);
          accA0 = fmaf(e1v, x10, accA0); accA1 = fmaf(e1v, x11, accA1);
          accA0 = fmaf(e2v, x20, accA0); accA1 = fmaf(e2v, x21, accA1);
          accA0 = fmaf(e3v, x30, accA0); accA1 = fmaf(e3v, x31, accA1);
          denA += (e0v + e1v) + (e2v + e3v);
        } else {
          accB0 = fmaf(e0v, x00, accB0); accB1 = fmaf(e0v, x01, accB1);
          accB0 = fmaf(e1v, x10, accB0); accB1 = fmaf(e1v, x11, accB1);
          accB0 = fmaf(e2v, x20, accB0); accB1 = fmaf(e2v, x21, accB1);
          accB0 = fmaf(e3v, x30, accB0); accB1 = fmaf(e3v, x31, accB1);
          denB += (e0v + e1v) + (e2v + e3v);
        }
      }
      float invA = 1.f / (denA + 1e-16f);
      float invB = 1.f / (denB + 1e-16f);
      hA0 = accA0 * invA + cbv.x; hA1 = accA1 * invA + cbv.y;
      hB0 = accB0 * invB + cbv.x; hB1 = accB1 * invB + cbv.y;
    } else {
      // rare fallback: pair window exceeds 64 edges -> solo path per node
      float accA0 = 0.f, accA1 = 0.f, denA = 0.f;
      float accB0 = 0.f, accB1 = 0.f, denB = 0.f;
      solo_node(e0A, e1A, l, esrc, xlb, eas4, up_lo(xruA), up_hi(xruA),
                w0, w1, attv, accA0, accA1, denA);
      solo_node(e1A, e1B, l, esrc, xlb, eas4, up_lo(xruB), up_hi(xruB),
                w0, w1, attv, accB0, accB1, denB);
      float invA = 1.f / (denA + 1e-16f);
      float invB = 1.f / (denB + 1e-16f);
      hA0 = accA0 * invA + cbv.x; hA1 = accA1 * invA + cbv.y;
      hB0 = accB0 * invB + cbv.x; hB1 = accB1 * invB + cbv.y;
    }
    *(float2*)&buf[(size_t)nA * H_ + c0] = make_float2(hA0, hA1);
    *(float2*)&buf[(size_t)nB * H_ + c0] = make_float2(hB0, hB1);
    a1_0 += hA0 + hB0; a1_1 += hA1 + hB1;
    a2_0 = fmaf(hA0, hA0, a2_0); a2_0 = fmaf(hB0, hB0, a2_0);
    a2_1 = fmaf(hA1, hA1, a2_1); a2_1 = fmaf(hB1, hB1, a2_1);
  }
  sA[t] = a1_0; sB[t] = a1_1; sC[t] = a2_0; sD[t] = a2_1;
  __syncthreads();
  if (t < 64) {
    float r1 = sA[t] + sA[t + 64] + sA[t + 128] + sA[t + 192];
    float r2 = sB[t] + sB[t + 64] + sB[t + 128] + sB[t + 192];
    float r3 = sC[t] + sC[t + 64] + sC[t + 128] + sC[t + 192];
    float r4 = sD[t] + sD[t + 64] + sD[t + 128] + sD[t + 192];
    atomicAdd(&ssum[2 * t], r1);
    atomicAdd(&ssum[2 * t + 1], r2);
    atomicAdd(&ssq[2 * t], r3);
    atomicAdd(&ssq[2 * t + 1], r4);
  }
}

// ---------------- pooling with fused layer-2 residual (inline BN finalize) ----
__global__ __launch_bounds__(128) void pool_residual(const int* __restrict__ goff,
                                                     const float* __restrict__ xn,
                                                     const float* __restrict__ buf,
                                                     const float* __restrict__ g,
                                                     const float* __restrict__ beta,
                                                     const float* __restrict__ ssum,
                                                     const float* __restrict__ ssq,
                                                     float rows_inv,
                                                     float* __restrict__ xg) {
  int gr = blockIdx.x;
  int t = threadIdx.x;
  int n0 = goff[gr], n1 = goff[gr + 1];
  float mm = ssum[t] * rows_inv;
  float rr = rsqrtf(ssq[t] * rows_inv - mm * mm + 1e-5f);
  float gg = g[t], bb = beta[t];
  float s = 0.f, mx = -INFINITY;
  for (int n = n0; n < n1; n++) {
    float w = gg * (buf[(size_t)n * H_ + t] - mm) * rr + bb;
    w = (w > 0.f) ? w : (__expf(w) - 1.f);
    float v = xn[(size_t)n * H_ + t] + w;
    s += v;
    mx = fmaxf(mx, v);
  }
  float c = (float)(n1 - n0);
  xg[gr * 384 + t] = s / fmaxf(c, 1.f);
  xg[gr * 384 + 128 + t] = (c > 0.f) ? mx : 0.f;
  xg[gr * 384 + 256 + t] = s;
}

// ---------------- t1 GEMM (raw output + colstats) ----------------
__global__ void mlp_gemm1(const float* __restrict__ A, const float* __restrict__ W,
                          const float* __restrict__ b, float* __restrict__ Y, int rows,
                          float* __restrict__ ssum, float* __restrict__ ssq) {
  __shared__ float xs[8][384];
  int t = threadIdx.x;  // 256
  int row0 = blockIdx.x * 8;
  for (int i = t; i < 8 * 384; i += 256) {
    int r = i / 384, k = i % 384;
    int row = row0 + r;
    xs[r][k] = (row < rows) ? A[row * 384 + k] : 0.f;
  }
  __syncthreads();
  float acc[8];
#pragma unroll
  for (int r = 0; r < 8; r++) acc[r] = 0.f;
  for (int k = 0; k < 384; k++) {
    float w = W[k * 256 + t];
#pragma unroll
    for (int r = 0; r < 8; r++) acc[r] = fmaf(xs[r][k], w, acc[r]);
  }
  float bb = b[t];
  float a1 = 0.f, a2 = 0.f;
#pragma unroll
  for (int r = 0; r < 8; r++) {
    int row = row0 + r;
    if (row < rows) {
      float v = acc[r] + bb;
      Y[row * 256 + t] = v;
      a1 += v;
      a2 = fmaf(v, v, a2);
    }
  }
  atomicAdd(&ssum[t], a1);
  atomicAdd(&ssq[t], a2);
}

// ---------------- t2 GEMM with inline BN+relu on input (u1 raw) -------------
__global__ void mlp_gemm2(const float* __restrict__ A,
                          const float* __restrict__ g4, const float* __restrict__ be4,
                          const float* __restrict__ s4, const float* __restrict__ q4,
                          float rinv,
                          const float* __restrict__ W, const float* __restrict__ b,
                          float* __restrict__ Y, int rows,
                          float* __restrict__ ssum, float* __restrict__ ssq) {
  __shared__ float xs[8][256];
  int t = threadIdx.x;  // 128
  int row0 = blockIdx.x * 8;
  for (int i = t; i < 8 * 256; i += 128) {
    int r = i >> 8, k = i & 255;
    int row = row0 + r;
    float v = 0.f;
    if (row < rows) {
      float m = s4[k] * rinv;
      float rs = rsqrtf(q4[k] * rinv - m * m + 1e-5f);
      v = fmaxf(g4[k] * (A[row * 256 + k] - m) * rs + be4[k], 0.f);
    }
    xs[r][k] = v;
  }
  __syncthreads();
  float acc[8];
#pragma unroll
  for (int r = 0; r < 8; r++) acc[r] = 0.f;
  for (int k = 0; k < 256; k++) {
    float w = W[k * 128 + t];
#pragma unroll
    for (int r = 0; r < 8; r++) acc[r] = fmaf(xs[r][k], w, acc[r]);
  }
  float bb = b[t];
  float a1 = 0.f, a2 = 0.f;
#pragma unroll
  for (int r = 0; r < 8; r++) {
    int row = row0 + r;
    if (row < rows) {
      float v = acc[r] + bb;
      Y[row * 128 + t] = v;
      a1 += v;
      a2 = fmaf(v, v, a2);
    }
  }
  atomicAdd(&ssum[t], a1);
  atomicAdd(&ssq[t], a2);
}

// ---------------- head with inline BN+relu on input (u2 raw) ----------------
__global__ __launch_bounds__(64) void head_kernel(const float* __restrict__ u,
                                                  const float* __restrict__ g5,
                                                  const float* __restrict__ be5,
                                                  const float* __restrict__ s5,
                                                  const float* __restrict__ q5,
                                                  float rinv,
                                                  const float* __restrict__ W,
                                                  const float* __restrict__ b,
                                                  float* __restrict__ out) {
  __shared__ float row[128];
  int gblk = blockIdx.x;
  int t = threadIdx.x;
#pragma unroll
  for (int h = 0; h < 2; h++) {
    int c = t + h * 64;
    float m = s5[c] * rinv;
    float rs = rsqrtf(q5[c] * rinv - m * m + 1e-5f);
    float v = g5[c] * (u[gblk * 128 + c] - m) * rs + be5[c];
    row[c] = fmaxf(v, 0.f);
  }
  __syncthreads();
  if (t < 12) {
    float acc = b[t];
    for (int k = 0; k < 128; k++) acc = fmaf(row[k], W[k * 12 + t], acc);
    out[gblk * 12 + t] = 1.f / (1.f + expf(-acc));
  }
}

// ---------------- launcher ----------------
extern "C" void kernel_launch(void* const* d_in, const int* in_sizes, int n_in, void* d_out,
                              int out_size, void* d_ws, size_t ws_size, hipStream_t stream) {
  (void)in_sizes; (void)n_in; (void)out_size; (void)ws_size;
  const float* x       = (const float*)d_in[0];
  const int*   ei      = (const int*)d_in[1];
  const float* ea      = (const float*)d_in[2];
  const int*   batch   = (const int*)d_in[3];
  const float* in_W    = (const float*)d_in[4];
  const float* in_b    = (const float*)d_in[5];
  const float* in_g    = (const float*)d_in[6];
  const float* in_beta = (const float*)d_in[7];
  const float* Wl      = (const float*)d_in[8];
  const float* Wr      = (const float*)d_in[9];
  const float* We      = (const float*)d_in[10];
  const float* att     = (const float*)d_in[11];
  const float* conv_b  = (const float*)d_in[12];
  const float* bn_g    = (const float*)d_in[13];
  const float* bn_b    = (const float*)d_in[14];
  const float* t1_W    = (const float*)d_in[15];
  const float* t1_b    = (const float*)d_in[16];
  const float* t1_g    = (const float*)d_in[17];
  const float* t1_beta = (const float*)d_in[18];
  const float* t2_W    = (const float*)d_in[19];
  const float* t2_b    = (const float*)d_in[20];
  const float* t2_g    = (const float*)d_in[21];
  const float* t2_beta = (const float*)d_in[22];
  const float* head_W  = (const float*)d_in[23];
  const float* head_b  = (const float*)d_in[24];
  float* out = (float*)d_out;

  float* p = (float*)d_ws;
  float* xn    = p; p += N_ * H_;
  float* buf   = p; p += N_ * H_;
  float* xg    = p; p += G_ * 384;
  float* u1    = p; p += G_ * 256;
  float* u2    = p; p += G_ * 128;
  float* sstat = p; p += 6 * 512;   // zeroed region starts here
  int* ip = (int*)p;
  int* deg    = ip; ip += N_;       // contiguous with sstat (one memset)
  int* pref   = ip; ip += 64;       // scan publish flags (zero-init sentinel)
  int* eoff   = ip; ip += N_ + 1;
  int* cursor = ip; ip += N_;
  int* goff   = ip; ip += G_ + 1;
  int* esrc   = ip; ip += E_;
  unsigned* up = (unsigned*)ip;
  unsigned* xlb  = up; up += (size_t)N_ * 64;
  unsigned* xrb  = up; up += (size_t)N_ * 64;
  unsigned* easb = up; up += (size_t)E_ * 4;
  unsigned short* wpack = (unsigned short*)up; up += 3 * 32768 / 2;

#define SSUM(s) (sstat + (s) * 512)
#define SSQ(s)  (sstat + (s) * 512 + 256)

  // single zeroing memset: sstat (12 KB) | deg (200 KB) | pref (256 B)
  hipMemsetAsync(sstat, 0, (size_t)(6 * 512 + N_ + 64) * sizeof(int), stream);

  // prep: hist + goff + pack_weights + in_gemm (stats -> stage 0)
  prep_kernel<<<HIST_B + GOFF_B + PACK_B + INGEMM_B, 256, 0, stream>>>(
      ei, batch, Wl, Wr, x, in_W, in_b, deg, goff, wpack, buf, SSUM(0), SSQ(0));

  // CSR: single-pass scan + scatter
  scan_onepass<<<49, 1024, 0, stream>>>(deg, eoff, cursor, pref, N_);
  edge_scatter<<<(E_ + 255) / 256, 256, 0, stream>>>(ei, ea, cursor, esrc, easb);

  // ---- 3 GATv2 layers (conv stats of layer l -> stage l+1) ----
  const float rnInv = 1.f / N_;
  for (int l = 0; l < 3; l++) {
    if (l == 0) {
      gemm_mfma<1><<<782, 256, 0, stream>>>(xn, buf, in_g, in_beta, SSUM(0), SSQ(0), rnInv,
                                            wpack + (size_t)l * 32768, xlb, xrb);
    } else {
      gemm_mfma<2><<<782, 256, 0, stream>>>(xn, buf, bn_g + (l - 1) * H_, bn_b + (l - 1) * H_,
                                            SSUM(l), SSQ(l), rnInv,
                                            wpack + (size_t)l * 32768, xlb, xrb);
    }
    agg_csr<<<2048, 256, 0, stream>>>(eoff, esrc, easb, We + l * 8 * H_, att + l * H_,
                                      xlb, xrb, conv_b + l * H_, buf, SSUM(l + 1), SSQ(l + 1));
  }

  // ---- pooling with fused layer-2 residual (stage 3 stats) ----
  pool_residual<<<G_, 128, 0, stream>>>(goff, xn, buf, bn_g + 2 * H_, bn_b + 2 * H_,
                                        SSUM(3), SSQ(3), rnInv, xg);

  // ---- t1 (raw + stats 4), t2 (inline BN of u1, raw + stats 5), head ----
  const float rgInv = 1.f / G_;
  mlp_gemm1<<<G_ / 8, 256, 0, stream>>>(xg, t1_W, t1_b, u1, G_, SSUM(4), SSQ(4));
  mlp_gemm2<<<G_ / 8, 128, 0, stream>>>(u1, t1_g, t1_beta, SSUM(4), SSQ(4), rgInv,
                                        t2_W, t2_b, u2, G_, SSUM(5), SSQ(5));
  head_kernel<<<G_, 64, 0, stream>>>(u2, t2_g, t2_beta, SSUM(5), SSQ(5), rgInv,
                                     head_W, head_b, out);
#undef SSUM
#undef SSQ
}